// Round 9
// baseline (200.371 us; speedup 1.0000x reference)
//
#include <hip/hip_runtime.h>

#define DEV __device__ __forceinline__

typedef unsigned short u16;
typedef unsigned int u32;
typedef __attribute__((ext_vector_type(4))) float f32x4;
typedef __attribute__((ext_vector_type(8))) short s16x8;
typedef __attribute__((ext_vector_type(8))) _Float16 f16x8;
typedef __attribute__((ext_vector_type(4))) unsigned short u16x4;
typedef __attribute__((ext_vector_type(4))) unsigned int u32x4;

#define BATCH 2
#define SEQ 2048
#define HID 1024
#define NH 16
#define HD 64

// scaling scheme (keeps fp16 lo-planes out of denormal range):
//  X' = 64*X, W' = 64*W  -> proj = acc/4096
//  q stored = proj_q * 8*log2e*4 (=46.1662), k stored = proj_k * 16
//  scores_mfma = 64 * (s * log2e); softmax uses sc*1/64 (FMA-fused w/ mask)
#define SCALE_XW 64.0f
#define INV_PROJ (1.0f / 4096.0f)
#define SCALE_Q 46.16624130844683f
#define SCALE_K 16.0f
#define SC_TO_LOG2 0.015625f
#define DEFER_THR 10.0f

DEV f32x4 mfmah(s16x8 a, s16x8 b, f32x4 c) {
    return __builtin_amdgcn_mfma_f32_16x16x32_f16(
        __builtin_bit_cast(f16x8, a), __builtin_bit_cast(f16x8, b), c, 0, 0, 0);
}

DEV u16 f2h(float x) { return __builtin_bit_cast(u16, (_Float16)x); }
DEV float h2f(u16 h) { return (float)__builtin_bit_cast(_Float16, h); }

DEV u32 pkh(float a, float b) {
#if __has_builtin(__builtin_amdgcn_cvt_pkrtz)
    auto r = __builtin_amdgcn_cvt_pkrtz(a, b);
    return __builtin_bit_cast(u32, r);
#else
    return (u32)f2h(a) | ((u32)f2h(b) << 16);
#endif
}

DEV float fexp2(float x) {
#if __has_builtin(__builtin_amdgcn_exp2f)
    return __builtin_amdgcn_exp2f(x);
#else
    return exp2f(x);
#endif
}

DEV void swap32(int lane, u32 a, u32 b, u32& o0, u32& o1) {
#if __has_builtin(__builtin_amdgcn_permlane32_swap)
    auto r = __builtin_amdgcn_permlane32_swap((int)a, (int)b, false, false);
    o0 = (u32)r[0]; o1 = (u32)r[1];
#else
    u32 ax = (u32)__shfl_xor((int)a, 32);
    u32 bx = (u32)__shfl_xor((int)b, 32);
    bool hi = (lane & 32) != 0;
    o0 = hi ? bx : a;
    o1 = hi ? b : ax;
#endif
}
DEV void swap16(int lane, u32 a, u32 b, u32& o0, u32& o1) {
#if __has_builtin(__builtin_amdgcn_permlane16_swap)
    auto r = __builtin_amdgcn_permlane16_swap((int)a, (int)b, false, false);
    o0 = (u32)r[0]; o1 = (u32)r[1];
#else
    u32 ax = (u32)__shfl_xor((int)a, 16);
    u32 bx = (u32)__shfl_xor((int)b, 16);
    bool hi = (lane & 16) != 0;
    o0 = hi ? bx : a;
    o1 = hi ? b : ax;
#endif
}

DEV void gl_lds16(const void* g, void* l) {
    __builtin_amdgcn_global_load_lds(
        (__attribute__((address_space(1))) void*)(void*)g,
        (__attribute__((address_space(3))) void*)l, 16, 0, 0);
}

// raw barrier pair (rule #18: sched_barrier fences around inline-asm waits)
DEV void vm0_bar() {
    __builtin_amdgcn_sched_barrier(0);
    asm volatile("s_waitcnt vmcnt(0)" ::: "memory");
    __builtin_amdgcn_s_barrier();
    __builtin_amdgcn_sched_barrier(0);
}

// counted barrier: oldest stage (7 loads/thread) guaranteed complete, newer 7
// stay in flight across the barrier (T4: never drain vmcnt to 0 mid-loop).
// lgkmcnt(0) closes the in-flight-ds_read vs DMA-restage race.
DEV void cbar7(bool last) {
    __builtin_amdgcn_sched_barrier(0);
    if (last)
        asm volatile("s_waitcnt vmcnt(0) lgkmcnt(0)" ::: "memory");
    else
        asm volatile("s_waitcnt vmcnt(7) lgkmcnt(0)" ::: "memory");
    __builtin_amdgcn_s_barrier();
    __builtin_amdgcn_sched_barrier(0);
}

// rows of 128B, 16B slots XOR-swizzled by row&7
DEV s16x8 lds_ld16(const u16* base, int row, int kbyte) {
    return *(const s16x8*)((const char*)base + row * 128 + (kbyte ^ ((row & 7) << 4)));
}
// rows of 64B, 16B slots XOR-swizzled by row&3
DEV s16x8 lds_ld32r(const u16* base, int row, int g) {
    return *(const s16x8*)((const char*)base + row * 64 + ((g * 16) ^ ((row & 3) << 4)));
}

// ---------------- mask: sniff dtype + convert to float bias ----------------
__global__ void detect_mask(const unsigned char* __restrict__ m, float* __restrict__ maskf) {
    __shared__ int sb, sf;
    if (threadIdx.x == 0) { sb = 0; sf = 0; }
    __syncthreads();
    int lb = 0, lf = 0;
    for (int i = threadIdx.x * 16; i < threadIdx.x * 16 + 16; i++) {
        unsigned char v = m[i];
        int pos = i & 3;
        if (pos == 3 && v == 0x3f) lf = 1;
        if (pos != 0 && v != 0) lb = 1;
    }
    if (lb) atomicOr(&sb, 1);
    if (lf) atomicOr(&sf, 1);
    __syncthreads();
    int f = sf ? 2 : (sb ? 1 : 0);
    for (int i = threadIdx.x; i < BATCH * SEQ; i += 256) {
        int mv;
        if (f == 0) mv = ((const int*)m)[i] != 0;
        else if (f == 1) mv = m[i] != 0;
        else mv = ((const float*)m)[i] != 0.0f;
        maskf[i] = mv ? -1e30f : 0.0f;
    }
}

// ---------------- prep: split (64*x) fp32 -> fp16 hi/lo ----------------
__global__ __launch_bounds__(256) void split_x(const float* __restrict__ in,
                                               u16* __restrict__ oh, u16* __restrict__ ol) {
    int i = (blockIdx.x * 256 + threadIdx.x) * 4;
    f32x4 v = *(const f32x4*)&in[i];
    u16x4 h, l;
#pragma unroll
    for (int e = 0; e < 4; e++) {
        float x = v[e] * SCALE_XW;
        u16 hi = f2h(x);
        h[e] = hi;
        l[e] = f2h(x - h2f(hi));
    }
    *(u16x4*)&oh[i] = h;
    *(u16x4*)&ol[i] = l;
}

// in[K][N] fp32 -> out_hi(/lo)[N][K] fp16 (transposed, scaled)
__global__ __launch_bounds__(256) void transpose_split(const float* __restrict__ in,
                                                       u16* __restrict__ oh, u16* __restrict__ ol,
                                                       int K, int N, float scale, int wlo) {
    __shared__ float t[32][33];
    int tx = threadIdx.x, ty = threadIdx.y;
    int n0 = blockIdx.x * 32, k0 = blockIdx.y * 32;
#pragma unroll
    for (int i = 0; i < 4; i++)
        t[ty + 8 * i][tx] = in[(size_t)(k0 + ty + 8 * i) * N + n0 + tx];
    __syncthreads();
#pragma unroll
    for (int i = 0; i < 4; i++) {
        float v = t[tx][ty + 8 * i] * scale;
        size_t o = (size_t)(n0 + ty + 8 * i) * K + k0 + tx;
        u16 hi = f2h(v);
        oh[o] = hi;
        if (wlo) ol[o] = f2h(v - h2f(hi));
    }
}

// ------- GEMM1: X' @ W' (fp16 split, 3 passes; V-tiles 2 passes) -------
// R7: SINGLE-buffered 32KB LDS -> 3 blocks/CU. Proven schedule.
__global__ __launch_bounds__(256, 3) void gemm_qkv(
    const u16* __restrict__ Xh, const u16* __restrict__ Xl,
    const u16* __restrict__ Wth, const u16* __restrict__ Wtl,
    const float* __restrict__ bqkv,
    u16* __restrict__ qh, u16* __restrict__ ql,
    u16* __restrict__ kh, u16* __restrict__ kl,
    u16* __restrict__ vt) {
    __shared__ __align__(16) u16 SM[4][128 * 32];  // 32 KB single buffer
    int tid = threadIdx.x, lane = tid & 63, w = tid >> 6;
    int g = lane >> 4, q15 = lane & 15;
    int wm = w >> 1, wn = w & 1;
    int m0 = blockIdx.y * 128, n0 = blockIdx.x * 128;
    int part = n0 >> 10;
    bool isV = (part == 2);  // V rounds to fp16 anyway: 2-pass error < fp16 ulp
    f32x4 acc[4][4];
#pragma unroll
    for (int i = 0; i < 4; i++)
#pragma unroll
        for (int j = 0; j < 4; j++) acc[i][j] = (f32x4){0.f, 0.f, 0.f, 0.f};

    auto STAGE = [&](int kt) {
        int k0 = kt * 32;
#pragma unroll
        for (int i = 0; i < 2; i++) {
            int c = i * 256 + tid;
            int row = c >> 2, slot = c & 3;
            int sg = slot ^ (row & 3);
            int dst = (c & ~63) * 8;
            size_t ga = (size_t)(m0 + row) * 1024 + k0 + sg * 8;
            size_t gb = (size_t)(n0 + row) * 1024 + k0 + sg * 8;
            gl_lds16(&Xh[ga], &SM[0][dst]);
            if (!isV) gl_lds16(&Xl[ga], &SM[1][dst]);
            gl_lds16(&Wth[gb], &SM[2][dst]);
            gl_lds16(&Wtl[gb], &SM[3][dst]);
        }
    };

    STAGE(0);
    for (int kt = 0; kt < 32; kt++) {
        vm0_bar();  // stage for kt complete on all waves
        s16x8 a_h[4], a_l[4], b_h[4], b_l[4];
#pragma unroll
        for (int i = 0; i < 4; i++) {
            a_h[i] = lds_ld32r(SM[0], wm * 64 + i * 16 + q15, g);
            if (!isV) a_l[i] = lds_ld32r(SM[1], wm * 64 + i * 16 + q15, g);
            b_h[i] = lds_ld32r(SM[2], wn * 64 + i * 16 + q15, g);
            b_l[i] = lds_ld32r(SM[3], wn * 64 + i * 16 + q15, g);
        }
        __syncthreads();  // all waves' reads retired -> buffer reusable
        if (kt < 31) STAGE(kt + 1);
#pragma unroll
        for (int mi = 0; mi < 4; mi++)
#pragma unroll
            for (int ni = 0; ni < 4; ni++) {
                acc[mi][ni] = mfmah(a_h[mi], b_h[ni], acc[mi][ni]);
                acc[mi][ni] = mfmah(a_h[mi], b_l[ni], acc[mi][ni]);
                if (!isV) acc[mi][ni] = mfmah(a_l[mi], b_h[ni], acc[mi][ni]);
            }
    }

    if (isV) {
        __syncthreads();  // all LDS reads done before SM reuse
        u16* T = (u16*)SM;
        // two 64-column half-passes (32KB buffer can't hold 128x136)
#pragma unroll
        for (int h2 = 0; h2 < 2; h2++) {
            __syncthreads();
            if (wn == h2) {
#pragma unroll
                for (int mi = 0; mi < 4; mi++)
#pragma unroll
                    for (int ni = 0; ni < 4; ni++) {
                        int lcol = ni * 16 + q15;  // 0..63 within half
#pragma unroll
                        for (int j = 0; j < 4; j++) {
                            int lrow = wm * 64 + mi * 16 + g * 4 + j;
                            T[lcol * 136 + lrow] =
                                f2h(acc[mi][ni][j] * INV_PROJ + bqkv[n0 + h2 * 64 + lcol]);
                        }
                    }
            }
            __syncthreads();
            int lcol = tid >> 2;  // 0..63
            int seg = tid & 3;
            int c = n0 - 2048 + h2 * 64 + lcol;
            int h = c >> 6, d = c & 63;
            int b = m0 >> 11, sbase = m0 & 2047;
            size_t rowbase = ((size_t)(b * NH + h) * HD + d) * SEQ + sbase;
#pragma unroll
            for (int k = 0; k < 2; k++) {
                int slot = seg * 2 + k;  // 8 slots x 16 rows = 128
                *(s16x8*)&vt[rowbase + slot * 16 + 0] = *(const s16x8*)&T[lcol * 136 + slot * 16 + 0];
                *(s16x8*)&vt[rowbase + slot * 16 + 8] = *(const s16x8*)&T[lcol * 136 + slot * 16 + 8];
            }
        }
    } else {
#pragma unroll
        for (int mi = 0; mi < 4; mi++)
#pragma unroll
            for (int ni = 0; ni < 4; ni++) {
                int col = n0 + wn * 64 + ni * 16 + q15;
                float bias = bqkv[col];
                int cc = col & 1023, h = cc >> 6, d = cc & 63;
#pragma unroll
                for (int j = 0; j < 4; j++) {
                    int row = m0 + wm * 64 + mi * 16 + g * 4 + j;
                    int b = row >> 11, s = row & 2047;
                    float v = acc[mi][ni][j] * INV_PROJ + bias;
                    v *= (part == 0) ? SCALE_Q : SCALE_K;
                    u16 hi = f2h(v);
                    u16 lo = f2h(v - h2f(hi));
                    size_t o = (size_t)(b * NH + h) * SEQ * HD + (size_t)s * HD + d;
                    if (part == 0) { qh[o] = hi; ql[o] = lo; }
                    else { kh[o] = hi; kl[o] = lo; }
                }
            }
    }
}

// ------ flash attention: R3 math, 3-slot rotating buffers + counted vmcnt(7) ------
// Stage kt+2 right after the barrier; barrier waits only the 2-iter-old stage.
// Loads/thread/stage uniform = 7 (Kh 2 + Kl 2 + V 2 + mask 1). No other VMEM
// in the loop (would corrupt the vmcnt FIFO accounting).
__global__ __launch_bounds__(256, 2) void attn_kernel(
    const u16* __restrict__ qh, const u16* __restrict__ ql,
    const u16* __restrict__ kh, const u16* __restrict__ kl,
    const u16* __restrict__ vt, const float* __restrict__ maskf,
    u16* __restrict__ att) {
    __shared__ __align__(16) u16 Kh[3][4096], Kl[3][4096], Vt[3][4096];  // 72 KB
    __shared__ __align__(16) float MskB[3][256];                          // 3 KB
    int tid = threadIdx.x, lane = tid & 63, w = tid >> 6;
    int g = lane >> 4, q15 = lane & 15;
    int bid = blockIdx.y * 16 + blockIdx.x;
    int swz = (bid & 7) * 64 + (bid >> 3);  // bijective: 512 % 8 == 0
    int qt = swz & 15, bh = swz >> 4;
    int b = bh >> 4, h = bh & 15;
    int q0 = qt * 128;
    size_t base = (size_t)bh * SEQ * HD;
    const u16* vbase = vt + (size_t)bh * HD * SEQ;
    const float* mrow = maskf + b * SEQ;

    // Q fragments, 2 groups of 16 rows (k-map: k = k2*32 + g*8 + e)
    s16x8 aqh[2][2], aql[2][2];
#pragma unroll
    for (int grp = 0; grp < 2; grp++)
#pragma unroll
        for (int k2 = 0; k2 < 2; k2++) {
            size_t o = base + (size_t)(q0 + w * 32 + grp * 16 + q15) * HD + k2 * 32 + g * 8;
            aqh[grp][k2] = *(const s16x8*)&qh[o];
            aql[grp][k2] = *(const s16x8*)&ql[o];
        }

    float m_[2] = {-1e30f, -1e30f}, l_[2] = {0.f, 0.f};  // l_ lane-partial
    f32x4 o_[2][4];
#pragma unroll
    for (int grp = 0; grp < 2; grp++)
#pragma unroll
        for (int df = 0; df < 4; df++) o_[grp][df] = (f32x4){0.f, 0.f, 0.f, 0.f};

    auto STAGE = [&](int buf, int k0) {
#pragma unroll
        for (int i = 0; i < 2; i++) {
            int c = i * 256 + tid;
            int row = c >> 3, slot = c & 7;
            int sg = slot ^ (row & 7);
            int dst = (c & ~63) * 8;
            size_t gK = base + (size_t)(k0 + row) * HD + sg * 8;
            gl_lds16(&kh[gK], &Kh[buf][dst]);
            gl_lds16(&kl[gK], &Kl[buf][dst]);
            size_t gV = (size_t)row * SEQ + k0 + sg * 8;
            gl_lds16(&vbase[gV], &Vt[buf][dst]);
        }
        // wave-wide mask stage (1KB, 4 waves redundant -> uniform 7 loads/thread;
        // reads 1KB from mrow[k0..] (maskf has 1KB slack); only [0..63] consumed.
        gl_lds16(&mrow[k0 + lane * 4], &MskB[buf][0]);
    };

    STAGE(0, 0);
    STAGE(1, 64);

    for (int kt = 0; kt < 32; kt++) {
        int cur = kt % 3;
        cbar7(kt == 31);  // stage(kt) complete; stage(kt+1) stays in flight
        if (kt < 30) STAGE((kt + 2) % 3, (kt + 2) * 64);

        // swapped QK^T both groups: D[k][q], k = nf*16 + g*4 + j, q = q15
        f32x4 sc0[4], sc1[4];
#pragma unroll
        for (int nf = 0; nf < 4; nf++) {
            sc0[nf] = (f32x4){0.f, 0.f, 0.f, 0.f};
            sc1[nf] = (f32x4){0.f, 0.f, 0.f, 0.f};
        }
#pragma unroll
        for (int nf = 0; nf < 4; nf++) {
#pragma unroll
            for (int k2 = 0; k2 < 2; k2++) {
                int kb = k2 * 64 + g * 16;
                s16x8 kbh = lds_ld16(Kh[cur], nf * 16 + q15, kb);
                s16x8 kbl = lds_ld16(Kl[cur], nf * 16 + q15, kb);
                sc0[nf] = mfmah(kbh, aqh[0][k2], sc0[nf]);
                sc0[nf] = mfmah(kbl, aqh[0][k2], sc0[nf]);
                sc0[nf] = mfmah(kbh, aql[0][k2], sc0[nf]);
                sc1[nf] = mfmah(kbh, aqh[1][k2], sc1[nf]);
                sc1[nf] = mfmah(kbl, aqh[1][k2], sc1[nf]);
                sc1[nf] = mfmah(kbh, aql[1][k2], sc1[nf]);
            }
            f32x4 mb = *(const f32x4*)&MskB[cur][nf * 16 + g * 4];
            sc0[nf] = sc0[nf] * SC_TO_LOG2 + mb;
            sc1[nf] = sc1[nf] * SC_TO_LOG2 + mb;
        }

        s16x8 pa[2][2];
#pragma unroll
        for (int grp = 0; grp < 2; grp++) {
            f32x4* sc = grp ? sc1 : sc0;
            float pml = -1e30f;
#pragma unroll
            for (int nf = 0; nf < 4; nf++)
#pragma unroll
                for (int j = 0; j < 4; j++) pml = fmaxf(pml, sc[nf][j]);
            // defer-max: skip rescale while tile max stays within THR of running max
            if (!__all(pml - m_[grp] <= DEFER_THR)) {
                float pm = fmaxf(pml, __shfl_xor(pml, 16));
                pm = fmaxf(pm, __shfl_xor(pm, 32));
                float mn = fmaxf(m_[grp], pm);
                float scl = fexp2(m_[grp] - mn);
                m_[grp] = mn;
                l_[grp] *= scl;
#pragma unroll
                for (int j = 0; j < 4; j++) {
                    float sb = __shfl(scl, g * 4 + j);
#pragma unroll
                    for (int df = 0; df < 4; df++) o_[grp][df][j] *= sb;
                }
            }
            float p[4][4];
            float rs = 0.f;
#pragma unroll
            for (int nf = 0; nf < 4; nf++)
#pragma unroll
                for (int j = 0; j < 4; j++) {
                    float pv = fexp2(sc[nf][j] - m_[grp]);
                    p[nf][j] = pv;
                    rs += pv;
                }
            l_[grp] += rs;  // lane-partial
            // in-register P repack: pa[k2] elem e = P[q15][k2*32 + g*8 + e]
#pragma unroll
            for (int k2 = 0; k2 < 2; k2++) {
                u32 A0 = pkh(p[2 * k2][0], p[2 * k2][1]);
                u32 A1 = pkh(p[2 * k2][2], p[2 * k2][3]);
                u32 B0 = pkh(p[2 * k2 + 1][0], p[2 * k2 + 1][1]);
                u32 B1 = pkh(p[2 * k2 + 1][2], p[2 * k2 + 1][3]);
                u32 s0, s1, t0, t1, w0, w1, w2, w3;
                swap32(lane, A0, B0, s0, s1);
                swap16(lane, s0, s1, w0, w2);
                swap32(lane, A1, B1, t0, t1);
                swap16(lane, t0, t1, w1, w3);
                u32x4 words = {w0, w1, w2, w3};
                pa[grp][k2] = __builtin_bit_cast(s16x8, words);
            }
        }

        // PV: O[q][d] += P[q][k] * V^T[d][k]  (vb shared by both groups)
#pragma unroll
        for (int k2 = 0; k2 < 2; k2++) {
            int kb = k2 * 64 + g * 16;
#pragma unroll
            for (int df = 0; df < 4; df++) {
                s16x8 vb = lds_ld16(Vt[cur], df * 16 + q15, kb);
                o_[0][df] = mfmah(pa[0][k2], vb, o_[0][df]);
                o_[1][df] = mfmah(pa[1][k2], vb, o_[1][df]);
            }
        }
    }

#pragma unroll
    for (int grp = 0; grp < 2; grp++) {
        float lt = l_[grp];
        lt += __shfl_xor(lt, 16);
        lt += __shfl_xor(lt, 32);
#pragma unroll
        for (int j = 0; j < 4; j++) {
            float lb = __shfl(lt, g * 4 + j);
            float linv = __builtin_amdgcn_rcpf(lb);
            int qrow = q0 + w * 32 + grp * 16 + g * 4 + j;
            size_t srow = (size_t)(b * SEQ + qrow);
#pragma unroll
            for (int df = 0; df < 4; df++) {
                int col = h * HD + df * 16 + q15;
                att[srow * HID + col] = f2h(o_[grp][df][j] * linv);
            }
        }
    }
}

// ---------------- GEMM2: att fp16 @ Wo fp16 (1 pass), 64x128 tiles, BK=32 dbuf -----
__global__ __launch_bounds__(256, 4) void gemm_out(
    const u16* __restrict__ A, const u16* __restrict__ Bh0,
    const float* __restrict__ bo, float* __restrict__ out) {
    __shared__ __align__(16) u16 SMa[2][64 * 32], SMb[2][128 * 32];  // 24 KB
    int tid = threadIdx.x, lane = tid & 63, w = tid >> 6;
    int g = lane >> 4, q15 = lane & 15;
    int wm = w >> 1, wn = w & 1;
    int m0 = blockIdx.y * 64, n0 = blockIdx.x * 128;
    f32x4 acc[2][4];
#pragma unroll
    for (int i = 0; i < 2; i++)
#pragma unroll
        for (int j = 0; j < 4; j++) acc[i][j] = (f32x4){0.f, 0.f, 0.f, 0.f};

    auto STAGE = [&](int db, int kt) {
        int k0 = kt * 32;
        {
            int c = tid;
            int row = c >> 2, slot = c & 3;
            int sg = slot ^ (row & 3);
            int dst = (c & ~63) * 8;
            gl_lds16(&A[(size_t)(m0 + row) * 1024 + k0 + sg * 8], &SMa[db][dst]);
        }
#pragma unroll
        for (int i = 0; i < 2; i++) {
            int c = i * 256 + tid;
            int row = c >> 2, slot = c & 3;
            int sg = slot ^ (row & 3);
            int dst = (c & ~63) * 8;
            gl_lds16(&Bh0[(size_t)(n0 + row) * 1024 + k0 + sg * 8], &SMb[db][dst]);
        }
    };

    STAGE(0, 0);
    for (int kt = 0; kt < 32; kt++) {
        int cur = kt & 1;
        __syncthreads();
        if (kt < 31) STAGE(cur ^ 1, kt + 1);
        s16x8 a_[2], b_[4];
#pragma unroll
        for (int i = 0; i < 2; i++)
            a_[i] = lds_ld32r(SMa[cur], wm * 32 + i * 16 + q15, g);
#pragma unroll
        for (int i = 0; i < 4; i++)
            b_[i] = lds_ld32r(SMb[cur], wn * 64 + i * 16 + q15, g);
#pragma unroll
        for (int mi = 0; mi < 2; mi++)
#pragma unroll
            for (int ni = 0; ni < 4; ni++)
                acc[mi][ni] = mfmah(a_[mi], b_[ni], acc[mi][ni]);
    }
#pragma unroll
    for (int mi = 0; mi < 2; mi++)
#pragma unroll
        for (int ni = 0; ni < 4; ni++) {
            int col = n0 + wn * 64 + ni * 16 + q15;
            float bias = bo[col];
#pragma unroll
            for (int j = 0; j < 4; j++) {
                int row = m0 + wm * 32 + mi * 16 + g * 4 + j;
                out[(size_t)row * 1024 + col] = acc[mi][ni][j] + bias;
            }
        }
}

extern "C" void kernel_launch(void* const* d_in, const int* in_sizes, int n_in,
                              void* d_out, int out_size, void* d_ws, size_t ws_size,
                              hipStream_t stream) {
    const float* qkv = (const float*)d_in[0];
    const void* mask = d_in[1];
    const float* Wqkv = (const float*)d_in[2];
    const float* bqkv = (const float*)d_in[3];
    const float* Wo = (const float*)d_in[4];
    const float* bo = (const float*)d_in[5];
    float* out = (float*)d_out;

    const size_t SZ_X = (size_t)4096 * 1024 * 2;       // 8 MB
    const size_t SZ_W = (size_t)3072 * 1024 * 2;       // 6 MB
    const size_t SZ_WO = (size_t)1024 * 1024 * 2;      // 2 MB
    const size_t SZ_QKV = (size_t)32 * 2048 * 64 * 2;  // 8 MB
    const size_t SZ_ATT = (size_t)4096 * 1024 * 2;     // 8 MB

    char* p = (char*)d_ws;
    u16* Xh = (u16*)p; p += SZ_X;
    u16* Xl = (u16*)p; p += SZ_X;
    u16* Wth = (u16*)p; p += SZ_W;
    u16* Wtl = (u16*)p; p += SZ_W;
    u16* Woth = (u16*)p; p += SZ_WO;
    u16* qh = (u16*)p; p += SZ_QKV;
    u16* ql = (u16*)p; p += SZ_QKV;
    u16* kh = (u16*)p; p += SZ_QKV;
    u16* kl = (u16*)p; p += SZ_QKV;
    u16* vt = (u16*)p; p += SZ_QKV;  // [bh][d][s]
    u16* att = (u16*)p; p += SZ_ATT;
    float* maskf = (float*)p; p += BATCH * SEQ * 4 + 1024;  // +1KB slack (mask stage reads 1KB)

    detect_mask<<<1, 256, 0, stream>>>((const unsigned char*)mask, maskf);
    split_x<<<4096, 256, 0, stream>>>(qkv, Xh, Xl);
    transpose_split<<<dim3(96, 32), dim3(32, 8), 0, stream>>>(Wqkv, Wth, Wtl, 1024, 3072,
                                                              SCALE_XW, 1);
    transpose_split<<<dim3(32, 32), dim3(32, 8), 0, stream>>>(Wo, Woth, nullptr, 1024, 1024,
                                                              1.0f, 0);
    gemm_qkv<<<dim3(24, 32), 256, 0, stream>>>(Xh, Xl, Wth, Wtl, bqkv, qh, ql, kh, kl, vt);
    attn_kernel<<<dim3(16, 32), 256, 0, stream>>>(qh, ql, kh, kl, vt, maskf, att);
    gemm_out<<<dim3(8, 64), 256, 0, stream>>>(att, Woth, bo, out);
}

// Round 10
// 184.411 us; speedup vs baseline: 1.0865x; 1.0865x over previous
//
#include <hip/hip_runtime.h>

#define DEV __device__ __forceinline__

typedef unsigned short u16;
typedef unsigned int u32;
typedef __attribute__((ext_vector_type(4))) float f32x4;
typedef __attribute__((ext_vector_type(8))) short s16x8;
typedef __attribute__((ext_vector_type(8))) _Float16 f16x8;
typedef __attribute__((ext_vector_type(4))) unsigned short u16x4;
typedef __attribute__((ext_vector_type(4))) unsigned int u32x4;

#define BATCH 2
#define SEQ 2048
#define HID 1024
#define NH 16
#define HD 64

// scaling scheme (keeps fp16 lo-planes out of denormal range):
//  X' = 64*X, W' = 64*W  -> proj = acc/4096
//  q stored = proj_q * 8*log2e*4 (=46.1662), k stored = proj_k * 16
//  scores_mfma = 64 * (s * log2e); softmax uses sc*1/64 (FMA-fused w/ mask)
#define SCALE_XW 64.0f
#define INV_PROJ (1.0f / 4096.0f)
#define SCALE_Q 46.16624130844683f
#define SCALE_K 16.0f
#define SC_TO_LOG2 0.015625f
#define DEFER_THR 10.0f

DEV f32x4 mfmah(s16x8 a, s16x8 b, f32x4 c) {
    return __builtin_amdgcn_mfma_f32_16x16x32_f16(
        __builtin_bit_cast(f16x8, a), __builtin_bit_cast(f16x8, b), c, 0, 0, 0);
}

DEV u16 f2h(float x) { return __builtin_bit_cast(u16, (_Float16)x); }
DEV float h2f(u16 h) { return (float)__builtin_bit_cast(_Float16, h); }

DEV u32 pkh(float a, float b) {
#if __has_builtin(__builtin_amdgcn_cvt_pkrtz)
    auto r = __builtin_amdgcn_cvt_pkrtz(a, b);
    return __builtin_bit_cast(u32, r);
#else
    return (u32)f2h(a) | ((u32)f2h(b) << 16);
#endif
}

DEV float fexp2(float x) {
#if __has_builtin(__builtin_amdgcn_exp2f)
    return __builtin_amdgcn_exp2f(x);
#else
    return exp2f(x);
#endif
}

DEV void swap32(int lane, u32 a, u32 b, u32& o0, u32& o1) {
#if __has_builtin(__builtin_amdgcn_permlane32_swap)
    auto r = __builtin_amdgcn_permlane32_swap((int)a, (int)b, false, false);
    o0 = (u32)r[0]; o1 = (u32)r[1];
#else
    u32 ax = (u32)__shfl_xor((int)a, 32);
    u32 bx = (u32)__shfl_xor((int)b, 32);
    bool hi = (lane & 32) != 0;
    o0 = hi ? bx : a;
    o1 = hi ? b : ax;
#endif
}
DEV void swap16(int lane, u32 a, u32 b, u32& o0, u32& o1) {
#if __has_builtin(__builtin_amdgcn_permlane16_swap)
    auto r = __builtin_amdgcn_permlane16_swap((int)a, (int)b, false, false);
    o0 = (u32)r[0]; o1 = (u32)r[1];
#else
    u32 ax = (u32)__shfl_xor((int)a, 16);
    u32 bx = (u32)__shfl_xor((int)b, 16);
    bool hi = (lane & 16) != 0;
    o0 = hi ? bx : a;
    o1 = hi ? b : ax;
#endif
}

DEV void gl_lds16(const void* g, void* l) {
    __builtin_amdgcn_global_load_lds(
        (__attribute__((address_space(1))) void*)(void*)g,
        (__attribute__((address_space(3))) void*)l, 16, 0, 0);
}

// raw barrier pair (rule #18: sched_barrier fences around inline-asm waits)
DEV void vm0_bar() {
    __builtin_amdgcn_sched_barrier(0);
    asm volatile("s_waitcnt vmcnt(0)" ::: "memory");
    __builtin_amdgcn_s_barrier();
    __builtin_amdgcn_sched_barrier(0);
}

// rows of 128B, 16B slots XOR-swizzled by row&7
DEV s16x8 lds_ld16(const u16* base, int row, int kbyte) {
    return *(const s16x8*)((const char*)base + row * 128 + (kbyte ^ ((row & 7) << 4)));
}
// rows of 64B, 16B slots XOR-swizzled by row&3
DEV s16x8 lds_ld32r(const u16* base, int row, int g) {
    return *(const s16x8*)((const char*)base + row * 64 + ((g * 16) ^ ((row & 3) << 4)));
}

// ---------------- mask: sniff dtype + convert to float bias ----------------
__global__ void detect_mask(const unsigned char* __restrict__ m, float* __restrict__ maskf) {
    __shared__ int sb, sf;
    if (threadIdx.x == 0) { sb = 0; sf = 0; }
    __syncthreads();
    int lb = 0, lf = 0;
    for (int i = threadIdx.x * 16; i < threadIdx.x * 16 + 16; i++) {
        unsigned char v = m[i];
        int pos = i & 3;
        if (pos == 3 && v == 0x3f) lf = 1;
        if (pos != 0 && v != 0) lb = 1;
    }
    if (lb) atomicOr(&sb, 1);
    if (lf) atomicOr(&sf, 1);
    __syncthreads();
    int f = sf ? 2 : (sb ? 1 : 0);
    for (int i = threadIdx.x; i < BATCH * SEQ; i += 256) {
        int mv;
        if (f == 0) mv = ((const int*)m)[i] != 0;
        else if (f == 1) mv = m[i] != 0;
        else mv = ((const float*)m)[i] != 0.0f;
        maskf[i] = mv ? -1e30f : 0.0f;
    }
}

// ---------------- prep: split (64*x) fp32 -> fp16 hi/lo ----------------
__global__ __launch_bounds__(256) void split_x(const float* __restrict__ in,
                                               u16* __restrict__ oh, u16* __restrict__ ol) {
    int i = (blockIdx.x * 256 + threadIdx.x) * 4;
    f32x4 v = *(const f32x4*)&in[i];
    u16x4 h, l;
#pragma unroll
    for (int e = 0; e < 4; e++) {
        float x = v[e] * SCALE_XW;
        u16 hi = f2h(x);
        h[e] = hi;
        l[e] = f2h(x - h2f(hi));
    }
    *(u16x4*)&oh[i] = h;
    *(u16x4*)&ol[i] = l;
}

// in[K][N] fp32 -> out_hi(/lo)[N][K] fp16 (transposed, scaled)
__global__ __launch_bounds__(256) void transpose_split(const float* __restrict__ in,
                                                       u16* __restrict__ oh, u16* __restrict__ ol,
                                                       int K, int N, float scale, int wlo) {
    __shared__ float t[32][33];
    int tx = threadIdx.x, ty = threadIdx.y;
    int n0 = blockIdx.x * 32, k0 = blockIdx.y * 32;
#pragma unroll
    for (int i = 0; i < 4; i++)
        t[ty + 8 * i][tx] = in[(size_t)(k0 + ty + 8 * i) * N + n0 + tx];
    __syncthreads();
#pragma unroll
    for (int i = 0; i < 4; i++) {
        float v = t[tx][ty + 8 * i] * scale;
        size_t o = (size_t)(n0 + ty + 8 * i) * K + k0 + tx;
        u16 hi = f2h(v);
        oh[o] = hi;
        if (wlo) ol[o] = f2h(v - h2f(hi));
    }
}

// ------- GEMM1: X' @ W' (fp16 split; passes Q/K/V = 3/2/2), BK=32 single-buf -------
// R7-proven schedule: vm0_bar -> ds_reads -> __syncthreads -> STAGE(kt+1) -> MFMAs.
// K now stores only the fp16 hi plane (attn dropped K-lo), so K tiles are 2-pass
// (2-pass product error 2^-22 << kh's own fp16 rounding 2^-11).
__global__ __launch_bounds__(256, 3) void gemm_qkv(
    const u16* __restrict__ Xh, const u16* __restrict__ Xl,
    const u16* __restrict__ Wth, const u16* __restrict__ Wtl,
    const float* __restrict__ bqkv,
    u16* __restrict__ qh, u16* __restrict__ ql,
    u16* __restrict__ kh,
    u16* __restrict__ vt) {
    __shared__ __align__(16) u16 SM[4][128 * 32];  // 32 KB single buffer
    int tid = threadIdx.x, lane = tid & 63, w = tid >> 6;
    int g = lane >> 4, q15 = lane & 15;
    int wm = w >> 1, wn = w & 1;
    int m0 = blockIdx.y * 128, n0 = blockIdx.x * 128;
    int part = n0 >> 10;
    bool lo3 = (part == 0);  // only Q needs the 3rd (lo) pass
    f32x4 acc[4][4];
#pragma unroll
    for (int i = 0; i < 4; i++)
#pragma unroll
        for (int j = 0; j < 4; j++) acc[i][j] = (f32x4){0.f, 0.f, 0.f, 0.f};

    auto STAGE = [&](int kt) {
        int k0 = kt * 32;
#pragma unroll
        for (int i = 0; i < 2; i++) {
            int c = i * 256 + tid;
            int row = c >> 2, slot = c & 3;
            int sg = slot ^ (row & 3);
            int dst = (c & ~63) * 8;
            size_t ga = (size_t)(m0 + row) * 1024 + k0 + sg * 8;
            size_t gb = (size_t)(n0 + row) * 1024 + k0 + sg * 8;
            gl_lds16(&Xh[ga], &SM[0][dst]);
            if (lo3) gl_lds16(&Xl[ga], &SM[1][dst]);
            gl_lds16(&Wth[gb], &SM[2][dst]);
            gl_lds16(&Wtl[gb], &SM[3][dst]);
        }
    };

    STAGE(0);
    for (int kt = 0; kt < 32; kt++) {
        vm0_bar();  // stage for kt complete on all waves
        s16x8 a_h[4], a_l[4], b_h[4], b_l[4];
#pragma unroll
        for (int i = 0; i < 4; i++) {
            a_h[i] = lds_ld32r(SM[0], wm * 64 + i * 16 + q15, g);
            if (lo3) a_l[i] = lds_ld32r(SM[1], wm * 64 + i * 16 + q15, g);
            b_h[i] = lds_ld32r(SM[2], wn * 64 + i * 16 + q15, g);
            b_l[i] = lds_ld32r(SM[3], wn * 64 + i * 16 + q15, g);
        }
        __syncthreads();  // all waves' reads retired -> buffer reusable
        if (kt < 31) STAGE(kt + 1);
#pragma unroll
        for (int mi = 0; mi < 4; mi++)
#pragma unroll
            for (int ni = 0; ni < 4; ni++) {
                acc[mi][ni] = mfmah(a_h[mi], b_h[ni], acc[mi][ni]);
                acc[mi][ni] = mfmah(a_h[mi], b_l[ni], acc[mi][ni]);
                if (lo3) acc[mi][ni] = mfmah(a_l[mi], b_h[ni], acc[mi][ni]);
            }
    }

    if (part == 2) {
        __syncthreads();  // all LDS reads done before SM reuse
        u16* T = (u16*)SM;
        // two 64-column half-passes (32KB buffer can't hold 128x136)
#pragma unroll
        for (int h2 = 0; h2 < 2; h2++) {
            __syncthreads();
            if (wn == h2) {
#pragma unroll
                for (int mi = 0; mi < 4; mi++)
#pragma unroll
                    for (int ni = 0; ni < 4; ni++) {
                        int lcol = ni * 16 + q15;  // 0..63 within half
#pragma unroll
                        for (int j = 0; j < 4; j++) {
                            int lrow = wm * 64 + mi * 16 + g * 4 + j;
                            T[lcol * 136 + lrow] =
                                f2h(acc[mi][ni][j] * INV_PROJ + bqkv[n0 + h2 * 64 + lcol]);
                        }
                    }
            }
            __syncthreads();
            int lcol = tid >> 2;  // 0..63
            int seg = tid & 3;
            int c = n0 - 2048 + h2 * 64 + lcol;
            int h = c >> 6, d = c & 63;
            int b = m0 >> 11, sbase = m0 & 2047;
            size_t rowbase = ((size_t)(b * NH + h) * HD + d) * SEQ + sbase;
#pragma unroll
            for (int k = 0; k < 2; k++) {
                int slot = seg * 2 + k;  // 8 slots x 16 rows = 128
                *(s16x8*)&vt[rowbase + slot * 16 + 0] = *(const s16x8*)&T[lcol * 136 + slot * 16 + 0];
                *(s16x8*)&vt[rowbase + slot * 16 + 8] = *(const s16x8*)&T[lcol * 136 + slot * 16 + 8];
            }
        }
    } else {
#pragma unroll
        for (int mi = 0; mi < 4; mi++)
#pragma unroll
            for (int ni = 0; ni < 4; ni++) {
                int col = n0 + wn * 64 + ni * 16 + q15;
                float bias = bqkv[col];
                int cc = col & 1023, h = cc >> 6, d = cc & 63;
#pragma unroll
                for (int j = 0; j < 4; j++) {
                    int row = m0 + wm * 64 + mi * 16 + g * 4 + j;
                    int b = row >> 11, s = row & 2047;
                    float v = acc[mi][ni][j] * INV_PROJ + bias;
                    v *= (part == 0) ? SCALE_Q : SCALE_K;
                    u16 hi = f2h(v);
                    size_t o = (size_t)(b * NH + h) * SEQ * HD + (size_t)s * HD + d;
                    if (part == 0) {
                        qh[o] = hi;
                        ql[o] = f2h(v - h2f(hi));
                    } else {
                        kh[o] = hi;  // K: single fp16 plane
                    }
                }
            }
    }
}

// ------ flash attention: R3-exact structure (proven 92.5us), K-lo dropped ------
// QK = (qh+ql)*kh: full-precision q x fp16 k. 32 QK MFMA + 16 PV MFMA per wave-iter,
// 8 K-reads + 8 V-reads. 2-phase dbuf, __syncthreads drain (R8's counted-vmcnt
// pipeline measured null -> reverted).
__global__ __launch_bounds__(256, 3) void attn_kernel(
    const u16* __restrict__ qh, const u16* __restrict__ ql,
    const u16* __restrict__ kh,
    const u16* __restrict__ vt, const float* __restrict__ maskf,
    u16* __restrict__ att) {
    __shared__ __align__(16) u16 Kh[2][4096], Vt[2][4096];  // 32 KB
    __shared__ __align__(16) float MskB[2][64];
    int tid = threadIdx.x, lane = tid & 63, w = tid >> 6;
    int g = lane >> 4, q15 = lane & 15;
    int bid = blockIdx.y * 16 + blockIdx.x;
    int swz = (bid & 7) * 64 + (bid >> 3);  // bijective: 512 % 8 == 0
    int qt = swz & 15, bh = swz >> 4;
    int b = bh >> 4, h = bh & 15;
    int q0 = qt * 128;
    size_t base = (size_t)bh * SEQ * HD;
    const u16* vbase = vt + (size_t)bh * HD * SEQ;
    const float* mrow = maskf + b * SEQ;

    // Q fragments, 2 groups of 16 rows (k-map: k = k2*32 + g*8 + e)
    s16x8 aqh[2][2], aql[2][2];
#pragma unroll
    for (int grp = 0; grp < 2; grp++)
#pragma unroll
        for (int k2 = 0; k2 < 2; k2++) {
            size_t o = base + (size_t)(q0 + w * 32 + grp * 16 + q15) * HD + k2 * 32 + g * 8;
            aqh[grp][k2] = *(const s16x8*)&qh[o];
            aql[grp][k2] = *(const s16x8*)&ql[o];
        }

    float m_[2] = {-1e30f, -1e30f}, l_[2] = {0.f, 0.f};  // l_ lane-partial
    f32x4 o_[2][4];
#pragma unroll
    for (int grp = 0; grp < 2; grp++)
#pragma unroll
        for (int df = 0; df < 4; df++) o_[grp][df] = (f32x4){0.f, 0.f, 0.f, 0.f};

    auto STAGE = [&](int buf, int k0) {
#pragma unroll
        for (int i = 0; i < 2; i++) {
            int c = i * 256 + tid;
            int row = c >> 3, slot = c & 7;
            int sg = slot ^ (row & 7);
            int dst = (c & ~63) * 8;
            size_t gK = base + (size_t)(k0 + row) * HD + sg * 8;
            gl_lds16(&kh[gK], &Kh[buf][dst]);
            size_t gV = (size_t)row * SEQ + k0 + sg * 8;
            gl_lds16(&vbase[gV], &Vt[buf][dst]);
        }
        if (tid < 16) gl_lds16(&mrow[k0 + tid * 4], &MskB[buf][0]);
    };

    STAGE(0, 0);
    __syncthreads();

    for (int kt = 0; kt < 32; kt++) {
        int cur = kt & 1;
        if (kt < 31) STAGE(cur ^ 1, (kt + 1) * 64);

        // swapped QK^T both groups: D[k][q], k = nf*16 + g*4 + j, q = q15
        f32x4 sc0[4], sc1[4];
#pragma unroll
        for (int nf = 0; nf < 4; nf++) {
            sc0[nf] = (f32x4){0.f, 0.f, 0.f, 0.f};
            sc1[nf] = (f32x4){0.f, 0.f, 0.f, 0.f};
        }
#pragma unroll
        for (int nf = 0; nf < 4; nf++) {
#pragma unroll
            for (int k2 = 0; k2 < 2; k2++) {
                int kb = k2 * 64 + g * 16;
                s16x8 kbh = lds_ld16(Kh[cur], nf * 16 + q15, kb);
                sc0[nf] = mfmah(kbh, aqh[0][k2], sc0[nf]);
                sc0[nf] = mfmah(kbh, aql[0][k2], sc0[nf]);
                sc1[nf] = mfmah(kbh, aqh[1][k2], sc1[nf]);
                sc1[nf] = mfmah(kbh, aql[1][k2], sc1[nf]);
            }
            f32x4 mb = *(const f32x4*)&MskB[cur][nf * 16 + g * 4];
            sc0[nf] = sc0[nf] * SC_TO_LOG2 + mb;
            sc1[nf] = sc1[nf] * SC_TO_LOG2 + mb;
        }

        s16x8 pa[2][2];
#pragma unroll
        for (int grp = 0; grp < 2; grp++) {
            f32x4* sc = grp ? sc1 : sc0;
            float pml = -1e30f;
#pragma unroll
            for (int nf = 0; nf < 4; nf++)
#pragma unroll
                for (int j = 0; j < 4; j++) pml = fmaxf(pml, sc[nf][j]);
            // defer-max: skip rescale while tile max stays within THR of running max
            if (!__all(pml - m_[grp] <= DEFER_THR)) {
                float pm = fmaxf(pml, __shfl_xor(pml, 16));
                pm = fmaxf(pm, __shfl_xor(pm, 32));
                float mn = fmaxf(m_[grp], pm);
                float scl = fexp2(m_[grp] - mn);
                m_[grp] = mn;
                l_[grp] *= scl;
#pragma unroll
                for (int j = 0; j < 4; j++) {
                    float sb = __shfl(scl, g * 4 + j);
#pragma unroll
                    for (int df = 0; df < 4; df++) o_[grp][df][j] *= sb;
                }
            }
            float p[4][4];
            float rs = 0.f;
#pragma unroll
            for (int nf = 0; nf < 4; nf++)
#pragma unroll
                for (int j = 0; j < 4; j++) {
                    float pv = fexp2(sc[nf][j] - m_[grp]);
                    p[nf][j] = pv;
                    rs += pv;
                }
            l_[grp] += rs;  // lane-partial
            // in-register P repack: pa[k2] elem e = P[q15][k2*32 + g*8 + e]
#pragma unroll
            for (int k2 = 0; k2 < 2; k2++) {
                u32 A0 = pkh(p[2 * k2][0], p[2 * k2][1]);
                u32 A1 = pkh(p[2 * k2][2], p[2 * k2][3]);
                u32 B0 = pkh(p[2 * k2 + 1][0], p[2 * k2 + 1][1]);
                u32 B1 = pkh(p[2 * k2 + 1][2], p[2 * k2 + 1][3]);
                u32 s0, s1, t0, t1, w0, w1, w2, w3;
                swap32(lane, A0, B0, s0, s1);
                swap16(lane, s0, s1, w0, w2);
                swap32(lane, A1, B1, t0, t1);
                swap16(lane, t0, t1, w1, w3);
                u32x4 words = {w0, w1, w2, w3};
                pa[grp][k2] = __builtin_bit_cast(s16x8, words);
            }
        }

        // PV: O[q][d] += P[q][k] * V^T[d][k]  (vb shared by both groups)
#pragma unroll
        for (int k2 = 0; k2 < 2; k2++) {
            int kb = k2 * 64 + g * 16;
#pragma unroll
            for (int df = 0; df < 4; df++) {
                s16x8 vb = lds_ld16(Vt[cur], df * 16 + q15, kb);
                o_[0][df] = mfmah(pa[0][k2], vb, o_[0][df]);
                o_[1][df] = mfmah(pa[1][k2], vb, o_[1][df]);
            }
        }
        __syncthreads();
    }

#pragma unroll
    for (int grp = 0; grp < 2; grp++) {
        float lt = l_[grp];
        lt += __shfl_xor(lt, 16);
        lt += __shfl_xor(lt, 32);
#pragma unroll
        for (int j = 0; j < 4; j++) {
            float lb = __shfl(lt, g * 4 + j);
            float linv = __builtin_amdgcn_rcpf(lb);
            int qrow = q0 + w * 32 + grp * 16 + g * 4 + j;
            size_t srow = (size_t)(b * SEQ + qrow);
#pragma unroll
            for (int df = 0; df < 4; df++) {
                int col = h * HD + df * 16 + q15;
                att[srow * HID + col] = f2h(o_[grp][df][j] * linv);
            }
        }
    }
}

// ---------------- GEMM2: att fp16 @ Wo fp16 (1 pass), 64x128 tiles, BK=32 dbuf -----
__global__ __launch_bounds__(256, 4) void gemm_out(
    const u16* __restrict__ A, const u16* __restrict__ Bh0,
    const float* __restrict__ bo, float* __restrict__ out) {
    __shared__ __align__(16) u16 SMa[2][64 * 32], SMb[2][128 * 32];  // 24 KB
    int tid = threadIdx.x, lane = tid & 63, w = tid >> 6;
    int g = lane >> 4, q15 = lane & 15;
    int wm = w >> 1, wn = w & 1;
    int m0 = blockIdx.y * 64, n0 = blockIdx.x * 128;
    f32x4 acc[2][4];
#pragma unroll
    for (int i = 0; i < 2; i++)
#pragma unroll
        for (int j = 0; j < 4; j++) acc[i][j] = (f32x4){0.f, 0.f, 0.f, 0.f};

    auto STAGE = [&](int db, int kt) {
        int k0 = kt * 32;
        {
            int c = tid;
            int row = c >> 2, slot = c & 3;
            int sg = slot ^ (row & 3);
            int dst = (c & ~63) * 8;
            gl_lds16(&A[(size_t)(m0 + row) * 1024 + k0 + sg * 8], &SMa[db][dst]);
        }
#pragma unroll
        for (int i = 0; i < 2; i++) {
            int c = i * 256 + tid;
            int row = c >> 2, slot = c & 3;
            int sg = slot ^ (row & 3);
            int dst = (c & ~63) * 8;
            gl_lds16(&Bh0[(size_t)(n0 + row) * 1024 + k0 + sg * 8], &SMb[db][dst]);
        }
    };

    STAGE(0, 0);
    for (int kt = 0; kt < 32; kt++) {
        int cur = kt & 1;
        __syncthreads();
        if (kt < 31) STAGE(cur ^ 1, kt + 1);
        s16x8 a_[2], b_[4];
#pragma unroll
        for (int i = 0; i < 2; i++)
            a_[i] = lds_ld32r(SMa[cur], wm * 32 + i * 16 + q15, g);
#pragma unroll
        for (int i = 0; i < 4; i++)
            b_[i] = lds_ld32r(SMb[cur], wn * 64 + i * 16 + q15, g);
#pragma unroll
        for (int mi = 0; mi < 2; mi++)
#pragma unroll
            for (int ni = 0; ni < 4; ni++)
                acc[mi][ni] = mfmah(a_[mi], b_[ni], acc[mi][ni]);
    }
#pragma unroll
    for (int mi = 0; mi < 2; mi++)
#pragma unroll
        for (int ni = 0; ni < 4; ni++) {
            int col = n0 + wn * 64 + ni * 16 + q15;
            float bias = bo[col];
#pragma unroll
            for (int j = 0; j < 4; j++) {
                int row = m0 + wm * 32 + mi * 16 + g * 4 + j;
                out[(size_t)row * 1024 + col] = acc[mi][ni][j] + bias;
            }
        }
}

extern "C" void kernel_launch(void* const* d_in, const int* in_sizes, int n_in,
                              void* d_out, int out_size, void* d_ws, size_t ws_size,
                              hipStream_t stream) {
    const float* qkv = (const float*)d_in[0];
    const void* mask = d_in[1];
    const float* Wqkv = (const float*)d_in[2];
    const float* bqkv = (const float*)d_in[3];
    const float* Wo = (const float*)d_in[4];
    const float* bo = (const float*)d_in[5];
    float* out = (float*)d_out;

    const size_t SZ_X = (size_t)4096 * 1024 * 2;       // 8 MB
    const size_t SZ_W = (size_t)3072 * 1024 * 2;       // 6 MB
    const size_t SZ_WO = (size_t)1024 * 1024 * 2;      // 2 MB
    const size_t SZ_QKV = (size_t)32 * 2048 * 64 * 2;  // 8 MB
    const size_t SZ_ATT = (size_t)4096 * 1024 * 2;     // 8 MB

    char* p = (char*)d_ws;
    u16* Xh = (u16*)p; p += SZ_X;
    u16* Xl = (u16*)p; p += SZ_X;
    u16* Wth = (u16*)p; p += SZ_W;
    u16* Wtl = (u16*)p; p += SZ_W;
    u16* Woth = (u16*)p; p += SZ_WO;
    u16* qh = (u16*)p; p += SZ_QKV;
    u16* ql = (u16*)p; p += SZ_QKV;
    u16* kh = (u16*)p; p += SZ_QKV;
    u16* vt = (u16*)p; p += SZ_QKV;  // [bh][d][s]
    u16* att = (u16*)p; p += SZ_ATT;
    float* maskf = (float*)p; p += BATCH * SEQ * 4;

    detect_mask<<<1, 256, 0, stream>>>((const unsigned char*)mask, maskf);
    split_x<<<4096, 256, 0, stream>>>(qkv, Xh, Xl);
    transpose_split<<<dim3(96, 32), dim3(32, 8), 0, stream>>>(Wqkv, Wth, Wtl, 1024, 3072,
                                                              SCALE_XW, 1);
    transpose_split<<<dim3(32, 32), dim3(32, 8), 0, stream>>>(Wo, Woth, nullptr, 1024, 1024,
                                                              1.0f, 0);
    gemm_qkv<<<dim3(24, 32), 256, 0, stream>>>(Xh, Xl, Wth, Wtl, bqkv, qh, ql, kh, vt);
    attn_kernel<<<dim3(16, 32), 256, 0, stream>>>(qh, ql, kh, vt, maskf, att);
    gemm_out<<<dim3(8, 64), 256, 0, stream>>>(att, Woth, bo, out);
}

// Round 11
// 163.238 us; speedup vs baseline: 1.2275x; 1.1297x over previous
//
#include <hip/hip_runtime.h>

#define DEV __device__ __forceinline__

typedef unsigned short u16;
typedef unsigned int u32;
typedef __attribute__((ext_vector_type(4))) float f32x4;
typedef __attribute__((ext_vector_type(8))) short s16x8;
typedef __attribute__((ext_vector_type(8))) _Float16 f16x8;
typedef __attribute__((ext_vector_type(4))) unsigned short u16x4;
typedef __attribute__((ext_vector_type(4))) unsigned int u32x4;

#define BATCH 2
#define SEQ 2048
#define HID 1024
#define NH 16
#define HD 64

// scaling scheme (keeps fp16 values in range):
//  X' = 64*X, W' = 64*W  -> proj = acc/4096
//  q stored = proj_q * 8*log2e*4 (=46.1662), k stored = proj_k * 16
//  scores_mfma = 64 * (s * log2e); softmax uses sc*1/64 (FMA-fused w/ mask)
// R10: q,k,x all single fp16 plane (score err sigma ~0.02 log2-units, absmax ~0.05
// vs threshold 0.107); W keeps hi/lo split (2-pass GEMM everywhere).
#define SCALE_XW 64.0f
#define INV_PROJ (1.0f / 4096.0f)
#define SCALE_Q 46.16624130844683f
#define SCALE_K 16.0f
#define SC_TO_LOG2 0.015625f
#define DEFER_THR 10.0f

DEV f32x4 mfmah(s16x8 a, s16x8 b, f32x4 c) {
    return __builtin_amdgcn_mfma_f32_16x16x32_f16(
        __builtin_bit_cast(f16x8, a), __builtin_bit_cast(f16x8, b), c, 0, 0, 0);
}

DEV u16 f2h(float x) { return __builtin_bit_cast(u16, (_Float16)x); }
DEV float h2f(u16 h) { return (float)__builtin_bit_cast(_Float16, h); }

DEV u32 pkh(float a, float b) {
#if __has_builtin(__builtin_amdgcn_cvt_pkrtz)
    auto r = __builtin_amdgcn_cvt_pkrtz(a, b);
    return __builtin_bit_cast(u32, r);
#else
    return (u32)f2h(a) | ((u32)f2h(b) << 16);
#endif
}

DEV float fexp2(float x) {
#if __has_builtin(__builtin_amdgcn_exp2f)
    return __builtin_amdgcn_exp2f(x);
#else
    return exp2f(x);
#endif
}

DEV void swap32(int lane, u32 a, u32 b, u32& o0, u32& o1) {
#if __has_builtin(__builtin_amdgcn_permlane32_swap)
    auto r = __builtin_amdgcn_permlane32_swap((int)a, (int)b, false, false);
    o0 = (u32)r[0]; o1 = (u32)r[1];
#else
    u32 ax = (u32)__shfl_xor((int)a, 32);
    u32 bx = (u32)__shfl_xor((int)b, 32);
    bool hi = (lane & 32) != 0;
    o0 = hi ? bx : a;
    o1 = hi ? b : ax;
#endif
}
DEV void swap16(int lane, u32 a, u32 b, u32& o0, u32& o1) {
#if __has_builtin(__builtin_amdgcn_permlane16_swap)
    auto r = __builtin_amdgcn_permlane16_swap((int)a, (int)b, false, false);
    o0 = (u32)r[0]; o1 = (u32)r[1];
#else
    u32 ax = (u32)__shfl_xor((int)a, 16);
    u32 bx = (u32)__shfl_xor((int)b, 16);
    bool hi = (lane & 16) != 0;
    o0 = hi ? bx : a;
    o1 = hi ? b : ax;
#endif
}

DEV void gl_lds16(const void* g, void* l) {
    __builtin_amdgcn_global_load_lds(
        (__attribute__((address_space(1))) void*)(void*)g,
        (__attribute__((address_space(3))) void*)l, 16, 0, 0);
}

// raw barrier pair (rule #18: sched_barrier fences around inline-asm waits)
DEV void vm0_bar() {
    __builtin_amdgcn_sched_barrier(0);
    asm volatile("s_waitcnt vmcnt(0)" ::: "memory");
    __builtin_amdgcn_s_barrier();
    __builtin_amdgcn_sched_barrier(0);
}

// rows of 128B, 16B slots XOR-swizzled by row&7
DEV s16x8 lds_ld16(const u16* base, int row, int kbyte) {
    return *(const s16x8*)((const char*)base + row * 128 + (kbyte ^ ((row & 7) << 4)));
}
// rows of 64B, 16B slots XOR-swizzled by row&3
DEV s16x8 lds_ld32r(const u16* base, int row, int g) {
    return *(const s16x8*)((const char*)base + row * 64 + ((g * 16) ^ ((row & 3) << 4)));
}

// ---------------- mask: sniff dtype + convert to float bias ----------------
__global__ void detect_mask(const unsigned char* __restrict__ m, float* __restrict__ maskf) {
    __shared__ int sb, sf;
    if (threadIdx.x == 0) { sb = 0; sf = 0; }
    __syncthreads();
    int lb = 0, lf = 0;
    for (int i = threadIdx.x * 16; i < threadIdx.x * 16 + 16; i++) {
        unsigned char v = m[i];
        int pos = i & 3;
        if (pos == 3 && v == 0x3f) lf = 1;
        if (pos != 0 && v != 0) lb = 1;
    }
    if (lb) atomicOr(&sb, 1);
    if (lf) atomicOr(&sf, 1);
    __syncthreads();
    int f = sf ? 2 : (sb ? 1 : 0);
    for (int i = threadIdx.x; i < BATCH * SEQ; i += 256) {
        int mv;
        if (f == 0) mv = ((const int*)m)[i] != 0;
        else if (f == 1) mv = m[i] != 0;
        else mv = ((const float*)m)[i] != 0.0f;
        maskf[i] = mv ? -1e30f : 0.0f;
    }
}

// ---------------- prep: scale+convert fp32 -> fp16 (single plane) ----------------
__global__ __launch_bounds__(256) void split_x(const float* __restrict__ in,
                                               u16* __restrict__ oh) {
    int i = (blockIdx.x * 256 + threadIdx.x) * 4;
    f32x4 v = *(const f32x4*)&in[i];
    u16x4 h;
#pragma unroll
    for (int e = 0; e < 4; e++) h[e] = f2h(v[e] * SCALE_XW);
    *(u16x4*)&oh[i] = h;
}

// in[K][N] fp32 -> out_hi(/lo)[N][K] fp16 (transposed, scaled)
__global__ __launch_bounds__(256) void transpose_split(const float* __restrict__ in,
                                                       u16* __restrict__ oh, u16* __restrict__ ol,
                                                       int K, int N, float scale, int wlo) {
    __shared__ float t[32][33];
    int tx = threadIdx.x, ty = threadIdx.y;
    int n0 = blockIdx.x * 32, k0 = blockIdx.y * 32;
#pragma unroll
    for (int i = 0; i < 4; i++)
        t[ty + 8 * i][tx] = in[(size_t)(k0 + ty + 8 * i) * N + n0 + tx];
    __syncthreads();
#pragma unroll
    for (int i = 0; i < 4; i++) {
        float v = t[tx][ty + 8 * i] * scale;
        size_t o = (size_t)(n0 + ty + 8 * i) * K + k0 + tx;
        u16 hi = f2h(v);
        oh[o] = hi;
        if (wlo) ol[o] = f2h(v - h2f(hi));
    }
}

// ------- GEMM1: Xh @ (Wh+Wl) fp16, uniform 2-pass, BK=32 single-buf 24KB -------
// R7-proven schedule: vm0_bar -> ds_reads -> __syncthreads -> STAGE(kt+1) -> MFMAs.
__global__ __launch_bounds__(256, 3) void gemm_qkv(
    const u16* __restrict__ Xh,
    const u16* __restrict__ Wth, const u16* __restrict__ Wtl,
    const float* __restrict__ bqkv,
    u16* __restrict__ qh,
    u16* __restrict__ kh,
    u16* __restrict__ vt) {
    __shared__ __align__(16) u16 SM[3][128 * 32];  // 24 KB single buffer
    int tid = threadIdx.x, lane = tid & 63, w = tid >> 6;
    int g = lane >> 4, q15 = lane & 15;
    int wm = w >> 1, wn = w & 1;
    int m0 = blockIdx.y * 128, n0 = blockIdx.x * 128;
    int part = n0 >> 10;
    f32x4 acc[4][4];
#pragma unroll
    for (int i = 0; i < 4; i++)
#pragma unroll
        for (int j = 0; j < 4; j++) acc[i][j] = (f32x4){0.f, 0.f, 0.f, 0.f};

    auto STAGE = [&](int kt) {
        int k0 = kt * 32;
#pragma unroll
        for (int i = 0; i < 2; i++) {
            int c = i * 256 + tid;
            int row = c >> 2, slot = c & 3;
            int sg = slot ^ (row & 3);
            int dst = (c & ~63) * 8;
            size_t ga = (size_t)(m0 + row) * 1024 + k0 + sg * 8;
            size_t gb = (size_t)(n0 + row) * 1024 + k0 + sg * 8;
            gl_lds16(&Xh[ga], &SM[0][dst]);
            gl_lds16(&Wth[gb], &SM[1][dst]);
            gl_lds16(&Wtl[gb], &SM[2][dst]);
        }
    };

    STAGE(0);
    for (int kt = 0; kt < 32; kt++) {
        vm0_bar();  // stage for kt complete on all waves
        s16x8 a_h[4], b_h[4], b_l[4];
#pragma unroll
        for (int i = 0; i < 4; i++) {
            a_h[i] = lds_ld32r(SM[0], wm * 64 + i * 16 + q15, g);
            b_h[i] = lds_ld32r(SM[1], wn * 64 + i * 16 + q15, g);
            b_l[i] = lds_ld32r(SM[2], wn * 64 + i * 16 + q15, g);
        }
        __syncthreads();  // all waves' reads retired -> buffer reusable
        if (kt < 31) STAGE(kt + 1);
#pragma unroll
        for (int mi = 0; mi < 4; mi++)
#pragma unroll
            for (int ni = 0; ni < 4; ni++) {
                acc[mi][ni] = mfmah(a_h[mi], b_h[ni], acc[mi][ni]);
                acc[mi][ni] = mfmah(a_h[mi], b_l[ni], acc[mi][ni]);
            }
    }

    if (part == 2) {
        __syncthreads();  // all LDS reads done before SM reuse
        u16* T = (u16*)SM;
        // two 64-column half-passes (64 x 136 u16 = 17.4 KB scratch)
#pragma unroll
        for (int h2 = 0; h2 < 2; h2++) {
            __syncthreads();
            if (wn == h2) {
#pragma unroll
                for (int mi = 0; mi < 4; mi++)
#pragma unroll
                    for (int ni = 0; ni < 4; ni++) {
                        int lcol = ni * 16 + q15;  // 0..63 within half
#pragma unroll
                        for (int j = 0; j < 4; j++) {
                            int lrow = wm * 64 + mi * 16 + g * 4 + j;
                            T[lcol * 136 + lrow] =
                                f2h(acc[mi][ni][j] * INV_PROJ + bqkv[n0 + h2 * 64 + lcol]);
                        }
                    }
            }
            __syncthreads();
            int lcol = tid >> 2;  // 0..63
            int seg = tid & 3;
            int c = n0 - 2048 + h2 * 64 + lcol;
            int h = c >> 6, d = c & 63;
            int b = m0 >> 11, sbase = m0 & 2047;
            size_t rowbase = ((size_t)(b * NH + h) * HD + d) * SEQ + sbase;
#pragma unroll
            for (int k = 0; k < 2; k++) {
                int slot = seg * 2 + k;  // 8 slots x 16 rows = 128
                *(s16x8*)&vt[rowbase + slot * 16 + 0] = *(const s16x8*)&T[lcol * 136 + slot * 16 + 0];
                *(s16x8*)&vt[rowbase + slot * 16 + 8] = *(const s16x8*)&T[lcol * 136 + slot * 16 + 8];
            }
        }
    } else {
#pragma unroll
        for (int mi = 0; mi < 4; mi++)
#pragma unroll
            for (int ni = 0; ni < 4; ni++) {
                int col = n0 + wn * 64 + ni * 16 + q15;
                float bias = bqkv[col];
                int cc = col & 1023, h = cc >> 6, d = cc & 63;
#pragma unroll
                for (int j = 0; j < 4; j++) {
                    int row = m0 + wm * 64 + mi * 16 + g * 4 + j;
                    int b = row >> 11, s = row & 2047;
                    float v = acc[mi][ni][j] * INV_PROJ + bias;
                    v *= (part == 0) ? SCALE_Q : SCALE_K;
                    size_t o = (size_t)(b * NH + h) * SEQ * HD + (size_t)s * HD + d;
                    if (part == 0) qh[o] = f2h(v);
                    else kh[o] = f2h(v);
                }
            }
    }
}

// ------ flash attention: 64-row q-tiles, 1 group/wave, 4 blocks/CU ------
// R10: q,k single fp16 plane -> QK = 8 MFMA + PV = 8 MFMA per wave-iter.
// Grid 32x32 = 1024 blocks -> 4 blocks/CU (LDS 33KB, VGPR capped by bounds(256,4)).
// 2-phase dbuf + __syncthreads (R8's counted-vmcnt measured null; R3 schedule kept).
__global__ __launch_bounds__(256, 4) void attn_kernel(
    const u16* __restrict__ qh,
    const u16* __restrict__ kh,
    const u16* __restrict__ vt, const float* __restrict__ maskf,
    u16* __restrict__ att) {
    __shared__ __align__(16) u16 Kh[2][4096], Vt[2][4096];  // 32 KB
    __shared__ __align__(16) float MskB[2][64];
    int tid = threadIdx.x, lane = tid & 63, w = tid >> 6;
    int g = lane >> 4, q15 = lane & 15;
    int bid = blockIdx.y * 32 + blockIdx.x;
    int swz = (bid & 7) * 128 + (bid >> 3);  // bijective: 1024 % 8 == 0
    int qt = swz & 31, bh = swz >> 5;        // 4 bh per XCD -> 2MB K+V, L2-resident
    int b = bh >> 4, h = bh & 15;
    int q0 = qt * 64;
    size_t base = (size_t)bh * SEQ * HD;
    const u16* vbase = vt + (size_t)bh * HD * SEQ;
    const float* mrow = maskf + b * SEQ;

    // Q fragments, 16 rows per wave (k-map: k = k2*32 + g*8 + e)
    s16x8 aq[2];
#pragma unroll
    for (int k2 = 0; k2 < 2; k2++) {
        size_t o = base + (size_t)(q0 + w * 16 + q15) * HD + k2 * 32 + g * 8;
        aq[k2] = *(const s16x8*)&qh[o];
    }

    float m_ = -1e30f, l_ = 0.f;  // l_ lane-partial
    f32x4 o_[4];
#pragma unroll
    for (int df = 0; df < 4; df++) o_[df] = (f32x4){0.f, 0.f, 0.f, 0.f};

    auto STAGE = [&](int buf, int k0) {
#pragma unroll
        for (int i = 0; i < 2; i++) {
            int c = i * 256 + tid;
            int row = c >> 3, slot = c & 7;
            int sg = slot ^ (row & 7);
            int dst = (c & ~63) * 8;
            size_t gK = base + (size_t)(k0 + row) * HD + sg * 8;
            gl_lds16(&kh[gK], &Kh[buf][dst]);
            size_t gV = (size_t)row * SEQ + k0 + sg * 8;
            gl_lds16(&vbase[gV], &Vt[buf][dst]);
        }
        if (tid < 16) gl_lds16(&mrow[k0 + tid * 4], &MskB[buf][0]);
    };

    STAGE(0, 0);
    __syncthreads();

    for (int kt = 0; kt < 32; kt++) {
        int cur = kt & 1;
        if (kt < 31) STAGE(cur ^ 1, (kt + 1) * 64);

        // swapped QK^T: D[k][q], k = nf*16 + g*4 + j, q = q15
        f32x4 sc[4];
#pragma unroll
        for (int nf = 0; nf < 4; nf++) sc[nf] = (f32x4){0.f, 0.f, 0.f, 0.f};
#pragma unroll
        for (int nf = 0; nf < 4; nf++) {
#pragma unroll
            for (int k2 = 0; k2 < 2; k2++) {
                int kb = k2 * 64 + g * 16;
                s16x8 kbh = lds_ld16(Kh[cur], nf * 16 + q15, kb);
                sc[nf] = mfmah(kbh, aq[k2], sc[nf]);
            }
            f32x4 mb = *(const f32x4*)&MskB[cur][nf * 16 + g * 4];
            sc[nf] = sc[nf] * SC_TO_LOG2 + mb;
        }

        // per-lane softmax (row q = q15) with defer-max
        float pml = -1e30f;
#pragma unroll
        for (int nf = 0; nf < 4; nf++)
#pragma unroll
            for (int j = 0; j < 4; j++) pml = fmaxf(pml, sc[nf][j]);
        if (!__all(pml - m_ <= DEFER_THR)) {
            float pm = fmaxf(pml, __shfl_xor(pml, 16));
            pm = fmaxf(pm, __shfl_xor(pm, 32));
            float mn = fmaxf(m_, pm);
            float scl = fexp2(m_ - mn);
            m_ = mn;
            l_ *= scl;
#pragma unroll
            for (int j = 0; j < 4; j++) {
                float sb = __shfl(scl, g * 4 + j);
#pragma unroll
                for (int df = 0; df < 4; df++) o_[df][j] *= sb;
            }
        }
        float p[4][4];
        float rs = 0.f;
#pragma unroll
        for (int nf = 0; nf < 4; nf++)
#pragma unroll
            for (int j = 0; j < 4; j++) {
                float pv = fexp2(sc[nf][j] - m_);
                p[nf][j] = pv;
                rs += pv;
            }
        l_ += rs;  // lane-partial
        // in-register P repack: pa[k2] elem e = P[q15][k2*32 + g*8 + e]
        s16x8 pa[2];
#pragma unroll
        for (int k2 = 0; k2 < 2; k2++) {
            u32 A0 = pkh(p[2 * k2][0], p[2 * k2][1]);
            u32 A1 = pkh(p[2 * k2][2], p[2 * k2][3]);
            u32 B0 = pkh(p[2 * k2 + 1][0], p[2 * k2 + 1][1]);
            u32 B1 = pkh(p[2 * k2 + 1][2], p[2 * k2 + 1][3]);
            u32 s0, s1, t0, t1, w0, w1, w2, w3;
            swap32(lane, A0, B0, s0, s1);
            swap16(lane, s0, s1, w0, w2);
            swap32(lane, A1, B1, t0, t1);
            swap16(lane, t0, t1, w1, w3);
            u32x4 words = {w0, w1, w2, w3};
            pa[k2] = __builtin_bit_cast(s16x8, words);
        }

        // PV: O[q][d] += P[q][k] * V^T[d][k]
#pragma unroll
        for (int k2 = 0; k2 < 2; k2++) {
            int kb = k2 * 64 + g * 16;
#pragma unroll
            for (int df = 0; df < 4; df++) {
                s16x8 vb = lds_ld16(Vt[cur], df * 16 + q15, kb);
                o_[df] = mfmah(pa[k2], vb, o_[df]);
            }
        }
        __syncthreads();
    }

    float lt = l_;
    lt += __shfl_xor(lt, 16);
    lt += __shfl_xor(lt, 32);
#pragma unroll
    for (int j = 0; j < 4; j++) {
        float lb = __shfl(lt, g * 4 + j);
        float linv = __builtin_amdgcn_rcpf(lb);
        int qrow = q0 + w * 16 + g * 4 + j;
        size_t srow = (size_t)(b * SEQ + qrow);
#pragma unroll
        for (int df = 0; df < 4; df++) {
            int col = h * HD + df * 16 + q15;
            att[srow * HID + col] = f2h(o_[df][j] * linv);
        }
    }
}

// ---------------- GEMM2: att fp16 @ Wo fp16 (1 pass), 64x128 tiles, BK=32 dbuf -----
__global__ __launch_bounds__(256, 4) void gemm_out(
    const u16* __restrict__ A, const u16* __restrict__ Bh0,
    const float* __restrict__ bo, float* __restrict__ out) {
    __shared__ __align__(16) u16 SMa[2][64 * 32], SMb[2][128 * 32];  // 24 KB
    int tid = threadIdx.x, lane = tid & 63, w = tid >> 6;
    int g = lane >> 4, q15 = lane & 15;
    int wm = w >> 1, wn = w & 1;
    int m0 = blockIdx.y * 64, n0 = blockIdx.x * 128;
    f32x4 acc[2][4];
#pragma unroll
    for (int i = 0; i < 2; i++)
#pragma unroll
        for (int j = 0; j < 4; j++) acc[i][j] = (f32x4){0.f, 0.f, 0.f, 0.f};

    auto STAGE = [&](int db, int kt) {
        int k0 = kt * 32;
        {
            int c = tid;
            int row = c >> 2, slot = c & 3;
            int sg = slot ^ (row & 3);
            int dst = (c & ~63) * 8;
            gl_lds16(&A[(size_t)(m0 + row) * 1024 + k0 + sg * 8], &SMa[db][dst]);
        }
#pragma unroll
        for (int i = 0; i < 2; i++) {
            int c = i * 256 + tid;
            int row = c >> 2, slot = c & 3;
            int sg = slot ^ (row & 3);
            int dst = (c & ~63) * 8;
            gl_lds16(&Bh0[(size_t)(n0 + row) * 1024 + k0 + sg * 8], &SMb[db][dst]);
        }
    };

    STAGE(0, 0);
    for (int kt = 0; kt < 32; kt++) {
        int cur = kt & 1;
        __syncthreads();
        if (kt < 31) STAGE(cur ^ 1, kt + 1);
        s16x8 a_[2], b_[4];
#pragma unroll
        for (int i = 0; i < 2; i++)
            a_[i] = lds_ld32r(SMa[cur], wm * 32 + i * 16 + q15, g);
#pragma unroll
        for (int i = 0; i < 4; i++)
            b_[i] = lds_ld32r(SMb[cur], wn * 64 + i * 16 + q15, g);
#pragma unroll
        for (int mi = 0; mi < 2; mi++)
#pragma unroll
            for (int ni = 0; ni < 4; ni++)
                acc[mi][ni] = mfmah(a_[mi], b_[ni], acc[mi][ni]);
    }
#pragma unroll
    for (int mi = 0; mi < 2; mi++)
#pragma unroll
        for (int ni = 0; ni < 4; ni++) {
            int col = n0 + wn * 64 + ni * 16 + q15;
            float bias = bo[col];
#pragma unroll
            for (int j = 0; j < 4; j++) {
                int row = m0 + wm * 32 + mi * 16 + g * 4 + j;
                out[(size_t)row * 1024 + col] = acc[mi][ni][j] + bias;
            }
        }
}

extern "C" void kernel_launch(void* const* d_in, const int* in_sizes, int n_in,
                              void* d_out, int out_size, void* d_ws, size_t ws_size,
                              hipStream_t stream) {
    const float* qkv = (const float*)d_in[0];
    const void* mask = d_in[1];
    const float* Wqkv = (const float*)d_in[2];
    const float* bqkv = (const float*)d_in[3];
    const float* Wo = (const float*)d_in[4];
    const float* bo = (const float*)d_in[5];
    float* out = (float*)d_out;

    const size_t SZ_X = (size_t)4096 * 1024 * 2;       // 8 MB
    const size_t SZ_W = (size_t)3072 * 1024 * 2;       // 6 MB
    const size_t SZ_WO = (size_t)1024 * 1024 * 2;      // 2 MB
    const size_t SZ_QKV = (size_t)32 * 2048 * 64 * 2;  // 8 MB
    const size_t SZ_ATT = (size_t)4096 * 1024 * 2;     // 8 MB

    char* p = (char*)d_ws;
    u16* Xh = (u16*)p; p += SZ_X;
    u16* Wth = (u16*)p; p += SZ_W;
    u16* Wtl = (u16*)p; p += SZ_W;
    u16* Woth = (u16*)p; p += SZ_WO;
    u16* qh = (u16*)p; p += SZ_QKV;
    u16* kh = (u16*)p; p += SZ_QKV;
    u16* vt = (u16*)p; p += SZ_QKV;  // [bh][d][s]
    u16* att = (u16*)p; p += SZ_ATT;
    float* maskf = (float*)p; p += BATCH * SEQ * 4;

    detect_mask<<<1, 256, 0, stream>>>((const unsigned char*)mask, maskf);
    split_x<<<4096, 256, 0, stream>>>(qkv, Xh);
    transpose_split<<<dim3(96, 32), dim3(32, 8), 0, stream>>>(Wqkv, Wth, Wtl, 1024, 3072,
                                                              SCALE_XW, 1);
    transpose_split<<<dim3(32, 32), dim3(32, 8), 0, stream>>>(Wo, Woth, nullptr, 1024, 1024,
                                                              1.0f, 0);
    gemm_qkv<<<dim3(24, 32), 256, 0, stream>>>(Xh, Wth, Wtl, bqkv, qh, kh, vt);
    attn_kernel<<<dim3(32, 32), 256, 0, stream>>>(qh, kh, vt, maskf, att);
    gemm_out<<<dim3(8, 64), 256, 0, stream>>>(att, Woth, bo, out);
}

// Round 12
// 128.539 us; speedup vs baseline: 1.5588x; 1.2699x over previous
//
#include <hip/hip_runtime.h>

#define DEV __device__ __forceinline__

typedef unsigned short u16;
typedef unsigned int u32;
typedef __attribute__((ext_vector_type(4))) float f32x4;
typedef __attribute__((ext_vector_type(8))) short s16x8;
typedef __attribute__((ext_vector_type(8))) _Float16 f16x8;
typedef __attribute__((ext_vector_type(4))) unsigned short u16x4;
typedef __attribute__((ext_vector_type(4))) unsigned int u32x4;

#define BATCH 2
#define SEQ 2048
#define HID 1024
#define NH 16
#define HD 64

// scaling scheme:  X' = 64*X, W' = 64*W -> proj = acc/4096
//  q stored = proj_q * 8*log2e*4, k stored = proj_k * 16
//  scores_mfma = 64 * (s * log2e); softmax uses sc*1/64 (FMA-fused w/ mask)
#define SCALE_XW 64.0f
#define INV_PROJ (1.0f / 4096.0f)
#define SCALE_Q 46.16624130844683f
#define SCALE_K 16.0f
#define SC_TO_LOG2 0.015625f
#define DEFER_THR 10.0f

DEV f32x4 mfmah(s16x8 a, s16x8 b, f32x4 c) {
    return __builtin_amdgcn_mfma_f32_16x16x32_f16(
        __builtin_bit_cast(f16x8, a), __builtin_bit_cast(f16x8, b), c, 0, 0, 0);
}

DEV u16 f2h(float x) { return __builtin_bit_cast(u16, (_Float16)x); }
DEV float h2f(u16 h) { return (float)__builtin_bit_cast(_Float16, h); }

DEV u32 pkh(float a, float b) {
#if __has_builtin(__builtin_amdgcn_cvt_pkrtz)
    auto r = __builtin_amdgcn_cvt_pkrtz(a, b);
    return __builtin_bit_cast(u32, r);
#else
    return (u32)f2h(a) | ((u32)f2h(b) << 16);
#endif
}

DEV float fexp2(float x) {
#if __has_builtin(__builtin_amdgcn_exp2f)
    return __builtin_amdgcn_exp2f(x);
#else
    return exp2f(x);
#endif
}

DEV void swap32(int lane, u32 a, u32 b, u32& o0, u32& o1) {
#if __has_builtin(__builtin_amdgcn_permlane32_swap)
    auto r = __builtin_amdgcn_permlane32_swap((int)a, (int)b, false, false);
    o0 = (u32)r[0]; o1 = (u32)r[1];
#else
    u32 ax = (u32)__shfl_xor((int)a, 32);
    u32 bx = (u32)__shfl_xor((int)b, 32);
    bool hi = (lane & 32) != 0;
    o0 = hi ? bx : a;
    o1 = hi ? b : ax;
#endif
}
DEV void swap16(int lane, u32 a, u32 b, u32& o0, u32& o1) {
#if __has_builtin(__builtin_amdgcn_permlane16_swap)
    auto r = __builtin_amdgcn_permlane16_swap((int)a, (int)b, false, false);
    o0 = (u32)r[0]; o1 = (u32)r[1];
#else
    u32 ax = (u32)__shfl_xor((int)a, 16);
    u32 bx = (u32)__shfl_xor((int)b, 16);
    bool hi = (lane & 16) != 0;
    o0 = hi ? bx : a;
    o1 = hi ? b : ax;
#endif
}

DEV void gl_lds16(const void* g, void* l) {
    __builtin_amdgcn_global_load_lds(
        (__attribute__((address_space(1))) void*)(void*)g,
        (__attribute__((address_space(3))) void*)l, 16, 0, 0);
}

// raw barrier pair (rule #18: sched_barrier fences around inline-asm waits)
DEV void vm0_bar() {
    __builtin_amdgcn_sched_barrier(0);
    asm volatile("s_waitcnt vmcnt(0)" ::: "memory");
    __builtin_amdgcn_s_barrier();
    __builtin_amdgcn_sched_barrier(0);
}

// rows of 128B, 16B slots XOR-swizzled by row&7
DEV s16x8 lds_ld16(const u16* base, int row, int kbyte) {
    return *(const s16x8*)((const char*)base + row * 128 + (kbyte ^ ((row & 7) << 4)));
}
// rows of 64B, 16B slots XOR-swizzled by row&3
DEV s16x8 lds_ld32r(const u16* base, int row, int g) {
    return *(const s16x8*)((const char*)base + row * 64 + ((g * 16) ^ ((row & 3) << 4)));
}

// ------- mask: sniff dtype, build key compaction (pack_idx/cnt) + packed bias -------
__global__ void detect_mask(const unsigned char* __restrict__ m, float* __restrict__ pbias,
                            int* __restrict__ pack_idx, int* __restrict__ cnt) {
    __shared__ int sb, sf;
    __shared__ int scan[256];
    int tid = threadIdx.x;
    if (tid == 0) { sb = 0; sf = 0; }
    __syncthreads();
    int lb = 0, lf = 0;
    for (int i = tid * 16; i < tid * 16 + 16; i++) {
        unsigned char v = m[i];
        int pos = i & 3;
        if (pos == 3 && v == 0x3f) lf = 1;
        if (pos != 0 && v != 0) lb = 1;
    }
    if (lb) atomicOr(&sb, 1);
    if (lf) atomicOr(&sf, 1);
    __syncthreads();
    int f = sf ? 2 : (sb ? 1 : 0);
#pragma unroll
    for (int b = 0; b < BATCH; b++) {
        int base = b * SEQ;
        int keep[8], lc = 0;
#pragma unroll
        for (int e = 0; e < 8; e++) {
            int i = base + tid * 8 + e;
            int mv;
            if (f == 0) mv = ((const int*)m)[i] != 0;
            else if (f == 1) mv = m[i] != 0;
            else mv = ((const float*)m)[i] != 0.0f;
            keep[e] = !mv;
            lc += keep[e];
        }
        scan[tid] = lc;
        __syncthreads();
        for (int s = 1; s < 256; s <<= 1) {
            int v = (tid >= s) ? scan[tid - s] : 0;
            __syncthreads();
            scan[tid] += v;
            __syncthreads();
        }
        int off = scan[tid] - lc;
        int total = scan[255];
        __syncthreads();  // scan reused next batch
#pragma unroll
        for (int e = 0; e < 8; e++)
            if (keep[e]) pack_idx[base + off++] = base + tid * 8 + e;
        if (tid == 0) cnt[b] = total;
        for (int j = tid; j < SEQ; j += 256)
            pbias[base + j] = (j < total) ? 0.0f : -1e30f;
    }
}

// ---------------- prep: scale+convert fp32 -> fp16 (single plane) ----------------
__global__ __launch_bounds__(256) void split_x(const float* __restrict__ in,
                                               u16* __restrict__ oh) {
    int i = (blockIdx.x * 256 + threadIdx.x) * 4;
    f32x4 v = *(const f32x4*)&in[i];
    u16x4 h;
#pragma unroll
    for (int e = 0; e < 4; e++) h[e] = f2h(v[e] * SCALE_XW);
    *(u16x4*)&oh[i] = h;
}

// in[K][N] fp32 -> out_hi(/lo)[N][K] fp16 (transposed, scaled)
__global__ __launch_bounds__(256) void transpose_split(const float* __restrict__ in,
                                                       u16* __restrict__ oh, u16* __restrict__ ol,
                                                       int K, int N, float scale, int wlo) {
    __shared__ float t[32][33];
    int tx = threadIdx.x, ty = threadIdx.y;
    int n0 = blockIdx.x * 32, k0 = blockIdx.y * 32;
#pragma unroll
    for (int i = 0; i < 4; i++)
        t[ty + 8 * i][tx] = in[(size_t)(k0 + ty + 8 * i) * N + n0 + tx];
    __syncthreads();
#pragma unroll
    for (int i = 0; i < 4; i++) {
        float v = t[tx][ty + 8 * i] * scale;
        size_t o = (size_t)(n0 + ty + 8 * i) * K + k0 + tx;
        u16 hi = f2h(v);
        oh[o] = hi;
        if (wlo) ol[o] = f2h(v - h2f(hi));
    }
}

// ------- GEMM1: Xh @ (Wh+Wl) fp16 2-pass, BK=32 single-buf 24KB -------
// R11: K/V parts operate in PACKED key space: source rows via pack_idx,
// m-blocks wholly beyond cnt[b] exit. Q part full-M, identity mapping.
__global__ __launch_bounds__(256, 3) void gemm_qkv(
    const u16* __restrict__ Xh,
    const u16* __restrict__ Wth, const u16* __restrict__ Wtl,
    const float* __restrict__ bqkv,
    const int* __restrict__ pack_idx, const int* __restrict__ cnt,
    u16* __restrict__ qh,
    u16* __restrict__ kh,
    u16* __restrict__ vt) {
    __shared__ __align__(16) u16 SM[3][128 * 32];  // 24 KB single buffer
    int tid = threadIdx.x, lane = tid & 63, w = tid >> 6;
    int g = lane >> 4, q15 = lane & 15;
    int wm = w >> 1, wn = w & 1;
    int m0 = blockIdx.y * 128, n0 = blockIdx.x * 128;
    int part = n0 >> 10;
    int bb = m0 >> 11;
    int cb = cnt[bb];
    if (part != 0 && (m0 & 2047) >= cb) return;  // packed rows all beyond count

    // fixed per-thread source-row map (2 rows/thread, constant across kt)
    int srcrow[2];
#pragma unroll
    for (int i = 0; i < 2; i++) {
        int r = m0 + ((i * 256 + tid) >> 2);
        srcrow[i] = (part == 0) ? r : (((r & 2047) < cb) ? pack_idx[r] : (bb << 11));
    }

    f32x4 acc[4][4];
#pragma unroll
    for (int i = 0; i < 4; i++)
#pragma unroll
        for (int j = 0; j < 4; j++) acc[i][j] = (f32x4){0.f, 0.f, 0.f, 0.f};

    auto STAGE = [&](int kt) {
        int k0 = kt * 32;
#pragma unroll
        for (int i = 0; i < 2; i++) {
            int c = i * 256 + tid;
            int row = c >> 2, slot = c & 3;
            int sg = slot ^ (row & 3);
            int dst = (c & ~63) * 8;
            size_t ga = (size_t)srcrow[i] * 1024 + k0 + sg * 8;
            size_t gb = (size_t)(n0 + row) * 1024 + k0 + sg * 8;
            gl_lds16(&Xh[ga], &SM[0][dst]);
            gl_lds16(&Wth[gb], &SM[1][dst]);
            gl_lds16(&Wtl[gb], &SM[2][dst]);
        }
    };

    STAGE(0);
    for (int kt = 0; kt < 32; kt++) {
        vm0_bar();  // stage for kt complete on all waves
        s16x8 a_h[4], b_h[4], b_l[4];
#pragma unroll
        for (int i = 0; i < 4; i++) {
            a_h[i] = lds_ld32r(SM[0], wm * 64 + i * 16 + q15, g);
            b_h[i] = lds_ld32r(SM[1], wn * 64 + i * 16 + q15, g);
            b_l[i] = lds_ld32r(SM[2], wn * 64 + i * 16 + q15, g);
        }
        __syncthreads();  // all waves' reads retired -> buffer reusable
        if (kt < 31) STAGE(kt + 1);
#pragma unroll
        for (int mi = 0; mi < 4; mi++)
#pragma unroll
            for (int ni = 0; ni < 4; ni++) {
                acc[mi][ni] = mfmah(a_h[mi], b_h[ni], acc[mi][ni]);
                acc[mi][ni] = mfmah(a_h[mi], b_l[ni], acc[mi][ni]);
            }
    }

    if (part == 2) {
        __syncthreads();  // all LDS reads done before SM reuse
        u16* T = (u16*)SM;
        // two 64-column half-passes; rows are PACKED s (tail garbage masked in attn)
#pragma unroll
        for (int h2 = 0; h2 < 2; h2++) {
            __syncthreads();
            if (wn == h2) {
#pragma unroll
                for (int mi = 0; mi < 4; mi++)
#pragma unroll
                    for (int ni = 0; ni < 4; ni++) {
                        int lcol = ni * 16 + q15;  // 0..63 within half
#pragma unroll
                        for (int j = 0; j < 4; j++) {
                            int lrow = wm * 64 + mi * 16 + g * 4 + j;
                            T[lcol * 136 + lrow] =
                                f2h(acc[mi][ni][j] * INV_PROJ + bqkv[n0 + h2 * 64 + lcol]);
                        }
                    }
            }
            __syncthreads();
            int lcol = tid >> 2;  // 0..63
            int seg = tid & 3;
            int c = n0 - 2048 + h2 * 64 + lcol;
            int h = c >> 6, d = c & 63;
            int b = m0 >> 11, sbase = m0 & 2047;
            size_t rowbase = ((size_t)(b * NH + h) * HD + d) * SEQ + sbase;
#pragma unroll
            for (int k = 0; k < 2; k++) {
                int slot = seg * 2 + k;  // 8 slots x 16 rows = 128
                *(s16x8*)&vt[rowbase + slot * 16 + 0] = *(const s16x8*)&T[lcol * 136 + slot * 16 + 0];
                *(s16x8*)&vt[rowbase + slot * 16 + 8] = *(const s16x8*)&T[lcol * 136 + slot * 16 + 8];
            }
        }
    } else {
#pragma unroll
        for (int mi = 0; mi < 4; mi++)
#pragma unroll
            for (int ni = 0; ni < 4; ni++) {
                int col = n0 + wn * 64 + ni * 16 + q15;
                float bias = bqkv[col];
                int cc = col & 1023, h = cc >> 6, d = cc & 63;
#pragma unroll
                for (int j = 0; j < 4; j++) {
                    int row = m0 + wm * 64 + mi * 16 + g * 4 + j;
                    int b = row >> 11, s = row & 2047;  // s: packed for K, true for Q
                    float v = acc[mi][ni][j] * INV_PROJ + bias;
                    v *= (part == 0) ? SCALE_Q : SCALE_K;
                    size_t o = (size_t)(b * NH + h) * SEQ * HD + (size_t)s * HD + d;
                    if (part == 0) qh[o] = f2h(v);
                    else kh[o] = f2h(v);
                }
            }
    }
}

// ------ flash attention over PACKED keys: NT = ceil(cnt[b]/64) tiles ------
// 64-row q-tiles, 4 blocks/CU, 2-phase dbuf (R3-proven schedule).
__global__ __launch_bounds__(256, 4) void attn_kernel(
    const u16* __restrict__ qh,
    const u16* __restrict__ kh,
    const u16* __restrict__ vt, const float* __restrict__ pbias,
    const int* __restrict__ cnt,
    u16* __restrict__ att) {
    __shared__ __align__(16) u16 Kh[2][4096], Vt[2][4096];  // 32 KB
    __shared__ __align__(16) float MskB[2][64];
    int tid = threadIdx.x, lane = tid & 63, w = tid >> 6;
    int g = lane >> 4, q15 = lane & 15;
    int bid = blockIdx.y * 32 + blockIdx.x;
    int swz = (bid & 7) * 128 + (bid >> 3);  // bijective: 1024 % 8 == 0
    int qt = swz & 31, bh = swz >> 5;        // 4 bh per XCD -> L2-resident K/V
    int b = bh >> 4, h = bh & 15;
    int q0 = qt * 64;
    int NT = (cnt[b] + 63) >> 6;  // packed key tiles
    size_t base = (size_t)bh * SEQ * HD;
    const u16* vbase = vt + (size_t)bh * HD * SEQ;
    const float* mrow = pbias + b * SEQ;

    // Q fragments, 16 rows per wave (k-map: k = k2*32 + g*8 + e)
    s16x8 aq[2];
#pragma unroll
    for (int k2 = 0; k2 < 2; k2++) {
        size_t o = base + (size_t)(q0 + w * 16 + q15) * HD + k2 * 32 + g * 8;
        aq[k2] = *(const s16x8*)&qh[o];
    }

    float m_ = -1e30f, l_ = 0.f;  // l_ lane-partial
    f32x4 o_[4];
#pragma unroll
    for (int df = 0; df < 4; df++) o_[df] = (f32x4){0.f, 0.f, 0.f, 0.f};

    auto STAGE = [&](int buf, int k0) {
#pragma unroll
        for (int i = 0; i < 2; i++) {
            int c = i * 256 + tid;
            int row = c >> 3, slot = c & 7;
            int sg = slot ^ (row & 7);
            int dst = (c & ~63) * 8;
            size_t gK = base + (size_t)(k0 + row) * HD + sg * 8;
            gl_lds16(&kh[gK], &Kh[buf][dst]);
            size_t gV = (size_t)row * SEQ + k0 + sg * 8;
            gl_lds16(&vbase[gV], &Vt[buf][dst]);
        }
        if (tid < 16) gl_lds16(&mrow[k0 + tid * 4], &MskB[buf][0]);
    };

    STAGE(0, 0);
    __syncthreads();

    for (int kt = 0; kt < NT; kt++) {
        int cur = kt & 1;
        if (kt < NT - 1) STAGE(cur ^ 1, (kt + 1) * 64);

        // swapped QK^T: D[k][q], k = nf*16 + g*4 + j, q = q15
        f32x4 sc[4];
#pragma unroll
        for (int nf = 0; nf < 4; nf++) sc[nf] = (f32x4){0.f, 0.f, 0.f, 0.f};
#pragma unroll
        for (int nf = 0; nf < 4; nf++) {
#pragma unroll
            for (int k2 = 0; k2 < 2; k2++) {
                int kb = k2 * 64 + g * 16;
                s16x8 kbh = lds_ld16(Kh[cur], nf * 16 + q15, kb);
                sc[nf] = mfmah(kbh, aq[k2], sc[nf]);
            }
            f32x4 mb = *(const f32x4*)&MskB[cur][nf * 16 + g * 4];
            sc[nf] = sc[nf] * SC_TO_LOG2 + mb;
        }

        // per-lane softmax (row q = q15) with defer-max
        float pml = -1e30f;
#pragma unroll
        for (int nf = 0; nf < 4; nf++)
#pragma unroll
            for (int j = 0; j < 4; j++) pml = fmaxf(pml, sc[nf][j]);
        if (!__all(pml - m_ <= DEFER_THR)) {
            float pm = fmaxf(pml, __shfl_xor(pml, 16));
            pm = fmaxf(pm, __shfl_xor(pm, 32));
            float mn = fmaxf(m_, pm);
            float scl = fexp2(m_ - mn);
            m_ = mn;
            l_ *= scl;
#pragma unroll
            for (int j = 0; j < 4; j++) {
                float sb = __shfl(scl, g * 4 + j);
#pragma unroll
                for (int df = 0; df < 4; df++) o_[df][j] *= sb;
            }
        }
        float p[4][4];
        float rs = 0.f;
#pragma unroll
        for (int nf = 0; nf < 4; nf++)
#pragma unroll
            for (int j = 0; j < 4; j++) {
                float pv = fexp2(sc[nf][j] - m_);
                p[nf][j] = pv;
                rs += pv;
            }
        l_ += rs;  // lane-partial
        // in-register P repack: pa[k2] elem e = P[q15][k2*32 + g*8 + e]
        s16x8 pa[2];
#pragma unroll
        for (int k2 = 0; k2 < 2; k2++) {
            u32 A0 = pkh(p[2 * k2][0], p[2 * k2][1]);
            u32 A1 = pkh(p[2 * k2][2], p[2 * k2][3]);
            u32 B0 = pkh(p[2 * k2 + 1][0], p[2 * k2 + 1][1]);
            u32 B1 = pkh(p[2 * k2 + 1][2], p[2 * k2 + 1][3]);
            u32 s0, s1, t0, t1, w0, w1, w2, w3;
            swap32(lane, A0, B0, s0, s1);
            swap16(lane, s0, s1, w0, w2);
            swap32(lane, A1, B1, t0, t1);
            swap16(lane, t0, t1, w1, w3);
            u32x4 words = {w0, w1, w2, w3};
            pa[k2] = __builtin_bit_cast(s16x8, words);
        }

        // PV: O[q][d] += P[q][k] * V^T[d][k]
#pragma unroll
        for (int k2 = 0; k2 < 2; k2++) {
            int kb = k2 * 64 + g * 16;
#pragma unroll
            for (int df = 0; df < 4; df++) {
                s16x8 vb = lds_ld16(Vt[cur], df * 16 + q15, kb);
                o_[df] = mfmah(pa[k2], vb, o_[df]);
            }
        }
        __syncthreads();
    }

    float lt = l_;
    lt += __shfl_xor(lt, 16);
    lt += __shfl_xor(lt, 32);
#pragma unroll
    for (int j = 0; j < 4; j++) {
        float lb = __shfl(lt, g * 4 + j);
        float linv = __builtin_amdgcn_rcpf(lb);
        int qrow = q0 + w * 16 + g * 4 + j;
        size_t srow = (size_t)(b * SEQ + qrow);
#pragma unroll
        for (int df = 0; df < 4; df++) {
            int col = h * HD + df * 16 + q15;
            att[srow * HID + col] = f2h(o_[df][j] * linv);
        }
    }
}

// ---------------- GEMM2: att fp16 @ Wo fp16 (1 pass), 64x128 tiles, BK=32 dbuf -----
__global__ __launch_bounds__(256, 4) void gemm_out(
    const u16* __restrict__ A, const u16* __restrict__ Bh0,
    const float* __restrict__ bo, float* __restrict__ out) {
    __shared__ __align__(16) u16 SMa[2][64 * 32], SMb[2][128 * 32];  // 24 KB
    int tid = threadIdx.x, lane = tid & 63, w = tid >> 6;
    int g = lane >> 4, q15 = lane & 15;
    int wm = w >> 1, wn = w & 1;
    int m0 = blockIdx.y * 64, n0 = blockIdx.x * 128;
    f32x4 acc[2][4];
#pragma unroll
    for (int i = 0; i < 2; i++)
#pragma unroll
        for (int j = 0; j < 4; j++) acc[i][j] = (f32x4){0.f, 0.f, 0.f, 0.f};

    auto STAGE = [&](int db, int kt) {
        int k0 = kt * 32;
        {
            int c = tid;
            int row = c >> 2, slot = c & 3;
            int sg = slot ^ (row & 3);
            int dst = (c & ~63) * 8;
            gl_lds16(&A[(size_t)(m0 + row) * 1024 + k0 + sg * 8], &SMa[db][dst]);
        }
#pragma unroll
        for (int i = 0; i < 2; i++) {
            int c = i * 256 + tid;
            int row = c >> 2, slot = c & 3;
            int sg = slot ^ (row & 3);
            int dst = (c & ~63) * 8;
            gl_lds16(&Bh0[(size_t)(n0 + row) * 1024 + k0 + sg * 8], &SMb[db][dst]);
        }
    };

    STAGE(0, 0);
    for (int kt = 0; kt < 32; kt++) {
        int cur = kt & 1;
        __syncthreads();
        if (kt < 31) STAGE(cur ^ 1, kt + 1);
        s16x8 a_[2], b_[4];
#pragma unroll
        for (int i = 0; i < 2; i++)
            a_[i] = lds_ld32r(SMa[cur], wm * 32 + i * 16 + q15, g);
#pragma unroll
        for (int i = 0; i < 4; i++)
            b_[i] = lds_ld32r(SMb[cur], wn * 64 + i * 16 + q15, g);
#pragma unroll
        for (int mi = 0; mi < 2; mi++)
#pragma unroll
            for (int ni = 0; ni < 4; ni++)
                acc[mi][ni] = mfmah(a_[mi], b_[ni], acc[mi][ni]);
    }
#pragma unroll
    for (int mi = 0; mi < 2; mi++)
#pragma unroll
        for (int ni = 0; ni < 4; ni++) {
            int col = n0 + wn * 64 + ni * 16 + q15;
            float bias = bo[col];
#pragma unroll
            for (int j = 0; j < 4; j++) {
                int row = m0 + wm * 32 + mi * 16 + g * 4 + j;
                out[(size_t)row * 1024 + col] = acc[mi][ni][j] + bias;
            }
        }
}

extern "C" void kernel_launch(void* const* d_in, const int* in_sizes, int n_in,
                              void* d_out, int out_size, void* d_ws, size_t ws_size,
                              hipStream_t stream) {
    const float* qkv = (const float*)d_in[0];
    const void* mask = d_in[1];
    const float* Wqkv = (const float*)d_in[2];
    const float* bqkv = (const float*)d_in[3];
    const float* Wo = (const float*)d_in[4];
    const float* bo = (const float*)d_in[5];
    float* out = (float*)d_out;

    const size_t SZ_X = (size_t)4096 * 1024 * 2;       // 8 MB
    const size_t SZ_W = (size_t)3072 * 1024 * 2;       // 6 MB
    const size_t SZ_WO = (size_t)1024 * 1024 * 2;      // 2 MB
    const size_t SZ_QKV = (size_t)32 * 2048 * 64 * 2;  // 8 MB
    const size_t SZ_ATT = (size_t)4096 * 1024 * 2;     // 8 MB

    char* p = (char*)d_ws;
    u16* Xh = (u16*)p; p += SZ_X;
    u16* Wth = (u16*)p; p += SZ_W;
    u16* Wtl = (u16*)p; p += SZ_W;
    u16* Woth = (u16*)p; p += SZ_WO;
    u16* qh = (u16*)p; p += SZ_QKV;
    u16* kh = (u16*)p; p += SZ_QKV;
    u16* vt = (u16*)p; p += SZ_QKV;  // [bh][d][s_packed]
    u16* att = (u16*)p; p += SZ_ATT;
    float* pbias = (float*)p; p += BATCH * SEQ * 4;
    int* pack_idx = (int*)p; p += BATCH * SEQ * 4;
    int* cnt = (int*)p; p += 256;

    detect_mask<<<1, 256, 0, stream>>>((const unsigned char*)mask, pbias, pack_idx, cnt);
    split_x<<<4096, 256, 0, stream>>>(qkv, Xh);
    transpose_split<<<dim3(96, 32), dim3(32, 8), 0, stream>>>(Wqkv, Wth, Wtl, 1024, 3072,
                                                              SCALE_XW, 1);
    transpose_split<<<dim3(32, 32), dim3(32, 8), 0, stream>>>(Wo, Woth, nullptr, 1024, 1024,
                                                              1.0f, 0);
    gemm_qkv<<<dim3(24, 32), 256, 0, stream>>>(Xh, Wth, Wtl, bqkv, pack_idx, cnt, qh, kh, vt);
    attn_kernel<<<dim3(32, 32), 256, 0, stream>>>(qh, kh, vt, pbias, cnt, att);
    gemm_out<<<dim3(8, 64), 256, 0, stream>>>(att, Woth, bo, out);
}